// Round 1
// baseline (473.070 us; speedup 1.0000x reference)
//
#include <hip/hip_runtime.h>
#include <math.h>

// NeuromorphicPrivacyNetwork: 3-layer LIF SNN, T=16, B=256, sizes 1024->2048->1024->512.
// Round-8: single-scheduling-round phase dispatches.
//   Theory: phase kernel VGPRs (~110-140) => <=4 blocks/CU => 1024 co-resident slots,
//   but grid was 1280 blocks => every dispatch took 2 scheduling rounds + tail (~19us).
//   Fix: (a) LIF roles do 8 elems/thread => grid 1280 -> 832 blocks,
//        (b) __launch_bounds__(256, 4) pins VGPR<=128 => guaranteed 4 blocks/CU,
//   so all 832 blocks are co-resident and each dispatch is one round (~9-11us predicted).
//   Pipeline schedule unchanged; 20 dispatches; phase d roles (all deps cross-dispatch):
//       bid [0,256)    L1-gemm-partial(t=d)
//       bid [256,384)  L1-lif(t=d-1)          (8 elems/thread)
//       bid [384,512)  L2-gemm-partial(t=d-2)
//       bid [512,576)  L2-lif(t=d-3) (+out)   (8 elems/thread)
//       bid [576,832)  L0-lif(s=d+1)          (8 elems/thread)
//   - no LDS in phase kernel; W1/W2 bf16; spikes bf16 {0,1}; partials fp32 slice-indexed
//   - trailing-window factor min(10, 17-t) folded into per-spike cost
//   - per-block non-atomic float2 cost buckets (stream-ordered across dispatches)

#define B 256
#define T_STEPS 16

typedef short short8 __attribute__((ext_vector_type(8)));
typedef float floatx4 __attribute__((ext_vector_type(4)));

__device__ inline ushort f2bf(float x) {
  unsigned int u = __float_as_uint(x);
  unsigned int r = (u + 0x7FFFu + ((u >> 16) & 1u)) >> 16;
  return (ushort)r;
}
__device__ inline float bf2f(ushort h) {
  return __uint_as_float(((unsigned int)h) << 16);
}
__device__ inline floatx4 mfma16(short8 a, short8 b, floatx4 c) {
  return __builtin_amdgcn_mfma_f32_16x16x32_bf16(a, b, c, 0, 0, 0);
}

// stage 16 fp32 -> hi/lo bf16 pairs into LDS (base0 setup GEMM only)
__device__ inline void stage_split16(const float* __restrict__ src, ushort* dsth, ushort* dstl) {
  float fv[16];
  #pragma unroll
  for (int i = 0; i < 4; ++i) *(float4*)&fv[4 * i] = *(const float4*)(src + 4 * i);
  unsigned int ph[8], pl[8];
  #pragma unroll
  for (int i = 0; i < 8; ++i) {
    ushort h0 = f2bf(fv[2 * i]);
    ushort l0 = f2bf(fv[2 * i] - bf2f(h0));
    ushort h1 = f2bf(fv[2 * i + 1]);
    ushort l1 = f2bf(fv[2 * i + 1] - bf2f(h1));
    ph[i] = (unsigned int)h0 | ((unsigned int)h1 << 16);
    pl[i] = (unsigned int)l0 | ((unsigned int)l1 << 16);
  }
  *(uint4*)dsth       = make_uint4(ph[0], ph[1], ph[2], ph[3]);
  *(uint4*)(dsth + 8) = make_uint4(ph[4], ph[5], ph[6], ph[7]);
  *(uint4*)dstl       = make_uint4(pl[0], pl[1], pl[2], pl[3]);
  *(uint4*)(dstl + 8) = make_uint4(pl[4], pl[5], pl[6], pl[7]);
}

// block-reduce then NON-ATOMIC accumulate into this block's private bucket.
// Same bid across successive dispatches is ordered by the stream -> no race.
__device__ inline void cost_accum_bucket(float csum, int cnt, float2* __restrict__ cbuf) {
  #pragma unroll
  for (int off = 32; off > 0; off >>= 1) {
    csum += __shfl_down(csum, off);
    cnt  += __shfl_down(cnt, off);
  }
  __shared__ float sc[4];
  __shared__ int   si[4];
  int wid = threadIdx.x >> 6;
  if ((threadIdx.x & 63) == 0) { sc[wid] = csum; si[wid] = cnt; }
  __syncthreads();
  if (threadIdx.x == 0) {
    float c = sc[0] + sc[1] + sc[2] + sc[3];
    int   k = si[0] + si[1] + si[2] + si[3];
    float2 v = cbuf[blockIdx.x];
    v.x += c * 0.01f;            // per-spike cost = 0.1 * fac/10 * wn = 0.01*fac*wn
    v.y += (float)k;
    cbuf[blockIdx.x] = v;
  }
}

// ---------------- weight row norms ----------------

__global__ __launch_bounds__(64) void wnorm_kernel(const float* __restrict__ w0,
                                                   const float* __restrict__ w1,
                                                   const float* __restrict__ w2,
                                                   float* __restrict__ wn) {
  int r = blockIdx.x;  // 0..3583
  const float* row; int K;
  if (r < 2048)      { row = w0 + (size_t)r * 1024;          K = 1024; }
  else if (r < 3072) { row = w1 + (size_t)(r - 2048) * 2048; K = 2048; }
  else               { row = w2 + (size_t)(r - 3072) * 1024; K = 1024; }
  float ss = 0.f;
  for (int k = threadIdx.x; k < K; k += 64) { float x = row[k]; ss += x * x; }
  #pragma unroll
  for (int off = 32; off > 0; off >>= 1) ss += __shfl_down(ss, off);
  if (threadIdx.x == 0) wn[r] = sqrtf(ss);
}

// ---------------- convert W1,W2 -> bf16 (+ zero the cost buckets) ----------------

__global__ __launch_bounds__(256) void convert_w_kernel(const float* __restrict__ w1,
                                                        const float* __restrict__ w2,
                                                        ushort* __restrict__ w1b,
                                                        ushort* __restrict__ w2b,
                                                        float2* __restrict__ cbuf) {
  if (blockIdx.x < 5) {   // 5*256 = 1280 buckets zeroed (only [0,832) used)
    cbuf[blockIdx.x * 256 + threadIdx.x] = make_float2(0.f, 0.f);
  }
  int i = (blockIdx.x * 256 + threadIdx.x) * 8;   // 1280 blocks -> 2621440 elems
  const float* src; ushort* dst;
  if (i < 2097152) { src = w1 + i; dst = w1b + i; }
  else             { src = w2 + (i - 2097152); dst = w2b + (i - 2097152); }
  float4 a = *(const float4*)src;
  float4 b = *(const float4*)(src + 4);
  unsigned int p0 = (unsigned int)f2bf(a.x) | ((unsigned int)f2bf(a.y) << 16);
  unsigned int p1 = (unsigned int)f2bf(a.z) | ((unsigned int)f2bf(a.w) << 16);
  unsigned int p2 = (unsigned int)f2bf(b.x) | ((unsigned int)f2bf(b.y) << 16);
  unsigned int p3 = (unsigned int)f2bf(b.z) | ((unsigned int)f2bf(b.w) << 16);
  *(uint4*)dst = make_uint4(p0, p1, p2, p3);
}

// ---------------- base0 = inputs @ w0^T via split MFMA (one-time) ----------------

__global__ __launch_bounds__(256) void base0_mfma_kernel(const float* __restrict__ A,  // [256][1024]
                                                         const float* __restrict__ W,  // [2048][1024]
                                                         float* __restrict__ C) {      // [256][2048]
  __shared__ ushort Ah[64][72], Al[64][72], Bh[64][72], Bl[64][72];
  const int tid = threadIdx.x;
  const int m0 = blockIdx.x * 64;
  const int n0 = blockIdx.y * 64;
  const int lane = tid & 63, wv = tid >> 6;
  const int wm = wv & 1, wn2 = wv >> 1;
  const int l15 = lane & 15, quad = lane >> 4;
  const int sr = tid >> 2, scol = (tid & 3) * 16;

  floatx4 acc[2][2];
  #pragma unroll
  for (int i = 0; i < 2; ++i)
    #pragma unroll
    for (int j = 0; j < 2; ++j) acc[i][j] = (floatx4){0.f, 0.f, 0.f, 0.f};

  for (int k0 = 0; k0 < 1024; k0 += 64) {
    stage_split16(A + (size_t)(m0 + sr) * 1024 + k0 + scol, &Ah[sr][scol], &Al[sr][scol]);
    stage_split16(W + (size_t)(n0 + sr) * 1024 + k0 + scol, &Bh[sr][scol], &Bl[sr][scol]);
    __syncthreads();
    #pragma unroll
    for (int ks = 0; ks < 2; ++ks) {
      short8 ah[2], al[2], bh[2], bl[2];
      #pragma unroll
      for (int s = 0; s < 2; ++s) {
        ah[s] = *(const short8*)&Ah[32 * wm + 16 * s + l15][ks * 32 + quad * 8];
        al[s] = *(const short8*)&Al[32 * wm + 16 * s + l15][ks * 32 + quad * 8];
        bh[s] = *(const short8*)&Bh[32 * wn2 + 16 * s + l15][ks * 32 + quad * 8];
        bl[s] = *(const short8*)&Bl[32 * wn2 + 16 * s + l15][ks * 32 + quad * 8];
      }
      #pragma unroll
      for (int sm = 0; sm < 2; ++sm)
        #pragma unroll
        for (int sn = 0; sn < 2; ++sn) {
          acc[sm][sn] = mfma16(ah[sm], bh[sn], acc[sm][sn]);
          acc[sm][sn] = mfma16(ah[sm], bl[sn], acc[sm][sn]);
          acc[sm][sn] = mfma16(al[sm], bh[sn], acc[sm][sn]);
        }
    }
    __syncthreads();
  }
  #pragma unroll
  for (int sm = 0; sm < 2; ++sm)
    #pragma unroll
    for (int sn = 0; sn < 2; ++sn)
      #pragma unroll
      for (int r = 0; r < 4; ++r) {
        int m = m0 + 32 * wm + 16 * sm + quad * 4 + r;
        int n = n0 + 32 * wn2 + 16 * sn + l15;
        C[(size_t)m * 2048 + n] = acc[sm][sn][r];
      }
}

// ---------------- params ----------------

struct StepParams {
  const float* base0; const float* cn0; const float* tn0; const float* th0; const float* wn0;
  float* V0; ushort* sp0a; ushort* sp0b;
  const ushort* w1b; const float* cn1; const float* tn1; const float* th1; const float* wn1;
  float* V1; ushort* sp1a; ushort* sp1b;
  const ushort* w2b; const float* cn2; const float* tn2; const float* th2; const float* wn2;
  float* V2; ushort* sp2a; ushort* sp2b;
  float* P1; float* P2;   // fp32 partials: P1[2][4][256][1024], P2[2][4][256][512]
  float* out; float2* cbuf;
};

// ---------------- partial GEMM: 64x64 tile over one K-slice, direct-global frags ----------

template<int K>
__device__ inline void ld_frags(const ushort* __restrict__ Abase,
                                const ushort* __restrict__ Wbase,
                                int l15, int k0, uint4 fa[2][2], uint4 fb[2][2]) {
  #pragma unroll
  for (int ks = 0; ks < 2; ++ks)
    #pragma unroll
    for (int s = 0; s < 2; ++s) {
      fa[ks][s] = *(const uint4*)(Abase + (size_t)(16 * s + l15) * K + k0 + ks * 32);
      fb[ks][s] = *(const uint4*)(Wbase + (size_t)(16 * s + l15) * K + k0 + ks * 32);
    }
}

template<int K, int N>
__device__ void gemm_partial(const ushort* __restrict__ A,   // [256][K] bf16 spikes
                             const ushort* __restrict__ W,   // [N][K] bf16
                             float* __restrict__ P,          // [4][256][N] fp32 (this parity)
                             int tile, int slice) {
  constexpr int SL = K / 4;           // K-slice length
  const int ks0 = slice * SL;
  const int tid = threadIdx.x;
  const int m0 = (tile & 3) * 64, n0 = (tile >> 2) * 64;
  const int lane = tid & 63, wv = tid >> 6;
  const int wm = wv & 1, wn2 = wv >> 1;
  const int l15 = lane & 15, quad = lane >> 4;

  const ushort* Abase = A + (size_t)(m0 + 32 * wm) * K + ks0 + quad * 8;
  const ushort* Wbase = W + (size_t)(n0 + 32 * wn2) * K + ks0 + quad * 8;

  floatx4 acc[2][2];
  #pragma unroll
  for (int i = 0; i < 2; ++i)
    #pragma unroll
    for (int j = 0; j < 2; ++j) acc[i][j] = (floatx4){0.f, 0.f, 0.f, 0.f};

  uint4 fa[2][2], fb[2][2];
  ld_frags<K>(Abase, Wbase, l15, 0, fa, fb);
  for (int k0 = 0; k0 < SL; k0 += 64) {
    uint4 na[2][2], nb[2][2];
    if (k0 + 64 < SL) ld_frags<K>(Abase, Wbase, l15, k0 + 64, na, nb);
    #pragma unroll
    for (int ks = 0; ks < 2; ++ks)
      #pragma unroll
      for (int sm = 0; sm < 2; ++sm)
        #pragma unroll
        for (int sn = 0; sn < 2; ++sn)
          acc[sm][sn] = mfma16(*(const short8*)&fa[ks][sm], *(const short8*)&fb[ks][sn], acc[sm][sn]);
    #pragma unroll
    for (int ks = 0; ks < 2; ++ks)
      #pragma unroll
      for (int s = 0; s < 2; ++s) { fa[ks][s] = na[ks][s]; fb[ks][s] = nb[ks][s]; }
  }

  float* Ps = P + (size_t)slice * 256 * N;
  #pragma unroll
  for (int sm = 0; sm < 2; ++sm)
    #pragma unroll
    for (int sn = 0; sn < 2; ++sn)
      #pragma unroll
      for (int r = 0; r < 4; ++r) {
        int m = m0 + 32 * wm + 16 * sm + quad * 4 + r;
        int n = n0 + 32 * wn2 + 16 * sn + l15;
        Ps[(size_t)m * N + n] = acc[sm][sn][r];
      }
}

// ---------------- LIF from 4 fp32 partials + noise (8 elems/thread) ----------------

template<int N, bool LAST>
__device__ void lif_partial(const float* __restrict__ P,     // [4][256][N] (this parity)
                            const ushort* __restrict__ sppr, // [256][N] prev spikes
                            ushort* __restrict__ spout,      // [256][N]
                            const float* __restrict__ cn, const float* __restrict__ tn,
                            const float* __restrict__ th, const float* __restrict__ wnv,
                            float* __restrict__ V, float* __restrict__ outF,
                            float2* __restrict__ cbuf, int t, int bid) {
  constexpr int SZ = 256 * N;
  float csum = 0.f; int cnt = 0;
  #pragma unroll
  for (int h = 0; h < 2; ++h) {
    int e = (bid * 256 + threadIdx.x) * 8 + h * 4;
    int n = e & (N - 1);
    size_t off = (size_t)(t - 1) * SZ + e;

    float4 a0 = *(const float4*)(P + e);
    float4 a1 = *(const float4*)(P + SZ + e);
    float4 a2 = *(const float4*)(P + 2 * SZ + e);
    float4 a3 = *(const float4*)(P + 3 * SZ + e);
    float4 c4  = *(const float4*)(cn + off);
    float4 t4  = *(const float4*)(tn + off);
    float4 th4 = *(const float4*)(th + n);
    float4 wn4 = *(const float4*)(wnv + n);
    float4 vv  = (t == 1) ? make_float4(0.f, 0.f, 0.f, 0.f) : *(const float4*)(V + e);
    ushort prv[4] = {0, 0, 0, 0};
    if (t > 1) { ushort4 pq = *(const ushort4*)(sppr + e); prv[0] = pq.x; prv[1] = pq.y; prv[2] = pq.z; prv[3] = pq.w; }

    float accv[4] = {a0.x + a1.x + a2.x + a3.x, a0.y + a1.y + a2.y + a3.y,
                     a0.z + a1.z + a2.z + a3.z, a0.w + a1.w + a2.w + a3.w};
    float vvv[4] = {vv.x, vv.y, vv.z, vv.w};
    float cnv[4] = {c4.x, c4.y, c4.z, c4.w};
    float tnv[4] = {t4.x, t4.y, t4.z, t4.w};
    float thv[4] = {th4.x, th4.y, th4.z, th4.w};
    float wnq[4] = {wn4.x, wn4.y, wn4.z, wn4.w};
    ushort sout[4]; float vout[4]; float oout[4];
    #pragma unroll
    for (int j = 0; j < 4; ++j) {
      float wnn = wnq[j];
      float cur = accv[j] + cnv[j] * (0.05f * wnn);
      bool refrac = (t > 1) && (prv[j] != 0);
      float Vn = refrac ? vvv[j] : (0.95f * vvv[j] + cur);
      float thr = thv[j] + tnv[j] * 0.1f;
      bool sp = (!refrac) && (Vn > thr);
      vout[j] = sp ? 0.f : Vn;
      sout[j] = sp ? (ushort)0x3F80 : (ushort)0;
      oout[j] = sp ? 1.f : 0.f;
      if (sp) { csum += wnn; cnt++; }
    }
    *(float4*)(V + e) = make_float4(vout[0], vout[1], vout[2], vout[3]);
    ushort4 sq; sq.x = sout[0]; sq.y = sout[1]; sq.z = sout[2]; sq.w = sout[3];
    *(ushort4*)(spout + e) = sq;
    if (LAST && t == T_STEPS) *(float4*)(outF + e) = make_float4(oout[0], oout[1], oout[2], oout[3]);
  }
  int f = 17 - t; if (f > 10) f = 10;
  cost_accum_bucket(csum * (float)f, cnt, cbuf);
}

// ---------------- L0 elementwise LIF (8 elems/thread) ----------------

__device__ void l0_role(const StepParams& p, int bid, int s) {
  const int tid = threadIdx.x;
  const ushort* pr = ((s - 1) & 1) ? p.sp0b : p.sp0a;
  ushort* so = (s & 1) ? p.sp0b : p.sp0a;
  float csum = 0.f; int cnt = 0;
  #pragma unroll
  for (int h = 0; h < 2; ++h) {
    int e = (bid * 256 + tid) * 8 + h * 4;   // 256 blocks cover 524288
    int n0i = e & 2047;
    size_t off = (size_t)(s - 1) * 524288 + e;

    float4 bb  = *(const float4*)(p.base0 + e);
    float4 c4  = *(const float4*)(p.cn0 + off);
    float4 t4  = *(const float4*)(p.tn0 + off);
    float4 th4 = *(const float4*)(p.th0 + n0i);
    float4 wn4 = *(const float4*)(p.wn0 + n0i);
    float4 vv  = (s == 1) ? make_float4(0.f, 0.f, 0.f, 0.f) : *(const float4*)(p.V0 + e);
    ushort prv[4] = {0, 0, 0, 0};
    if (s > 1) { ushort4 pq = *(const ushort4*)(pr + e); prv[0] = pq.x; prv[1] = pq.y; prv[2] = pq.z; prv[3] = pq.w; }

    float bbv[4] = {bb.x, bb.y, bb.z, bb.w};
    float vvv[4] = {vv.x, vv.y, vv.z, vv.w};
    float cnv[4] = {c4.x, c4.y, c4.z, c4.w};
    float tnv[4] = {t4.x, t4.y, t4.z, t4.w};
    float thv[4] = {th4.x, th4.y, th4.z, th4.w};
    float wnq[4] = {wn4.x, wn4.y, wn4.z, wn4.w};
    ushort sout[4]; float vout[4];
    #pragma unroll
    for (int j = 0; j < 4; ++j) {
      float wnn = wnq[j];
      float cur = bbv[j] + cnv[j] * (0.05f * wnn);
      bool refrac = (s > 1) && (prv[j] != 0);
      float Vn = refrac ? vvv[j] : (0.95f * vvv[j] + cur);
      float thr = thv[j] + tnv[j] * 0.1f;
      bool sp = (!refrac) && (Vn > thr);
      vout[j] = sp ? 0.f : Vn;
      sout[j] = sp ? (ushort)0x3F80 : (ushort)0;
      if (sp) { csum += wnn; cnt++; }
    }
    *(float4*)(p.V0 + e) = make_float4(vout[0], vout[1], vout[2], vout[3]);
    ushort4 sq; sq.x = sout[0]; sq.y = sout[1]; sq.z = sout[2]; sq.w = sout[3];
    *(ushort4*)(so + e) = sq;
  }
  int f = 17 - s; if (f > 10) f = 10;
  cost_accum_bucket(csum * (float)f, cnt, p.cbuf);
}

// ---------------- phase kernel: 5 roles, all deps cross-dispatch ----------------
// __launch_bounds__(256, 4): force VGPR<=128 so 4 blocks/CU co-reside => 1024 slots,
// grid is 832 blocks => every dispatch runs in ONE scheduling round.

__global__ __launch_bounds__(256, 4) void phase_kernel(StepParams p, int d) {
  const int bid = blockIdx.x;
  if (bid < 256) {
    int t = d;                                   // L1 partial GEMM
    if (t >= 1 && t <= 16) {
      const ushort* A = (t & 1) ? p.sp0b : p.sp0a;
      float* P = p.P1 + (size_t)(t & 1) * 1048576;
      gemm_partial<2048, 1024>(A, p.w1b, P, bid & 63, bid >> 6);
    }
  } else if (bid < 384) {
    int t = d - 1;                               // L1 LIF from partials (128 blocks)
    if (t >= 1 && t <= 16) {
      const float* P = p.P1 + (size_t)(t & 1) * 1048576;
      const ushort* pr = ((t - 1) & 1) ? p.sp1b : p.sp1a;
      ushort* so = (t & 1) ? p.sp1b : p.sp1a;
      lif_partial<1024, false>(P, pr, so, p.cn1, p.tn1, p.th1, p.wn1, p.V1, nullptr,
                               p.cbuf, t, bid - 256);
    }
  } else if (bid < 512) {
    int t2 = d - 2;                              // L2 partial GEMM (128 blocks)
    if (t2 >= 1 && t2 <= 16) {
      const ushort* A = (t2 & 1) ? p.sp1b : p.sp1a;
      float* P = p.P2 + (size_t)(t2 & 1) * 524288;
      int b2 = bid - 384;
      gemm_partial<1024, 512>(A, p.w2b, P, b2 & 31, b2 >> 5);
    }
  } else if (bid < 576) {
    int t2 = d - 3;                              // L2 LIF from partials (+ out at t=16), 64 blocks
    if (t2 >= 1 && t2 <= 16) {
      const float* P = p.P2 + (size_t)(t2 & 1) * 524288;
      const ushort* pr = ((t2 - 1) & 1) ? p.sp2b : p.sp2a;
      ushort* so = (t2 & 1) ? p.sp2b : p.sp2a;
      lif_partial<512, true>(P, pr, so, p.cn2, p.tn2, p.th2, p.wn2, p.V2, p.out,
                             p.cbuf, t2, bid - 512);
    }
  } else {
    int s = d + 1;                               // L0 elementwise LIF (256 blocks)
    if (s <= 16) l0_role(p, bid - 576, s);
  }
}

// ---------------- finalize: reduce buckets -> cost, entropy ----------------

__global__ __launch_bounds__(256) void finalize_kernel(const float2* __restrict__ cbuf,
                                                       float* __restrict__ out) {
  float c = 0.f, k = 0.f;
  for (int i = threadIdx.x; i < 1280; i += 256) {
    float2 v = cbuf[i];
    c += v.x; k += v.y;
  }
  #pragma unroll
  for (int off = 32; off > 0; off >>= 1) {
    c += __shfl_down(c, off);
    k += __shfl_down(k, off);
  }
  __shared__ float sc[4], sk[4];
  int wid = threadIdx.x >> 6;
  if ((threadIdx.x & 63) == 0) { sc[wid] = c; sk[wid] = k; }
  __syncthreads();
  if (threadIdx.x == 0) {
    float cost = sc[0] + sc[1] + sc[2] + sc[3];
    float tot  = sk[0] + sk[1] + sk[2] + sk[3];
    float p1 = tot / 14680064.f;   // T*B*(2048+1024+512)
    float p0 = 1.f - p1;
    float ent = -(p1 * log2f(p1 + 1e-12f) + p0 * log2f(p0 + 1e-12f));
    out[131072] = cost;
    out[131073] = ent;
  }
}

// ---------------- launch ----------------

extern "C" void kernel_launch(void* const* d_in, const int* in_sizes, int n_in,
                              void* d_out, int out_size, void* d_ws, size_t ws_size,
                              hipStream_t stream) {
  const float* inputs = (const float*)d_in[0];
  const float* w0  = (const float*)d_in[1];
  const float* th0 = (const float*)d_in[2];
  const float* cn0 = (const float*)d_in[3];
  const float* tn0 = (const float*)d_in[4];
  const float* w1  = (const float*)d_in[5];
  const float* th1 = (const float*)d_in[6];
  const float* cn1 = (const float*)d_in[7];
  const float* tn1 = (const float*)d_in[8];
  const float* w2  = (const float*)d_in[9];
  const float* th2 = (const float*)d_in[10];
  const float* cn2 = (const float*)d_in[11];
  const float* tn2 = (const float*)d_in[12];
  float* out = (float*)d_out;
  float* ws  = (float*)d_ws;

  // workspace layout (float slots), total ~6.83M floats = ~26 MB
  float* wn    = ws;                    // 3584: wn0[2048] wn1[1024] wn2[512]
  float* base0 = ws + 4096;             // 524288
  float* V0    = base0 + 524288;        // 524288
  float* V1    = V0 + 524288;           // 262144
  float* V2    = V1 + 262144;           // 131072
  ushort* w1b  = (ushort*)(V2 + 131072);        // 2097152 ushort
  ushort* w2b  = w1b + 2097152;                 // 524288 ushort
  ushort* sp0a = w2b + 524288;                  // 524288 ushort each
  ushort* sp0b = sp0a + 524288;
  ushort* sp1a = sp0b + 524288;                 // 262144 ushort each
  ushort* sp1b = sp1a + 262144;
  ushort* sp2a = sp1b + 262144;                 // 131072 ushort each
  ushort* sp2b = sp2a + 131072;
  float* P1 = (float*)(sp2b + 131072);          // 2097152 floats (both parities)
  float* P2 = P1 + 2097152;                     // 1048576 floats
  float2* cbuf = (float2*)(P2 + 1048576);       // 1280 float2

  wnorm_kernel<<<3584, 64, 0, stream>>>(w0, w1, w2, wn);
  convert_w_kernel<<<1280, 256, 0, stream>>>(w1, w2, w1b, w2b, cbuf);
  base0_mfma_kernel<<<dim3(4, 32), 256, 0, stream>>>(inputs, w0, base0);

  StepParams p;
  p.base0 = base0; p.cn0 = cn0; p.tn0 = tn0; p.th0 = th0; p.wn0 = wn;
  p.V0 = V0; p.sp0a = sp0a; p.sp0b = sp0b;
  p.w1b = w1b; p.cn1 = cn1; p.tn1 = tn1; p.th1 = th1; p.wn1 = wn + 2048;
  p.V1 = V1; p.sp1a = sp1a; p.sp1b = sp1b;
  p.w2b = w2b; p.cn2 = cn2; p.tn2 = tn2; p.th2 = th2; p.wn2 = wn + 3072;
  p.V2 = V2; p.sp2a = sp2a; p.sp2b = sp2b;
  p.P1 = P1; p.P2 = P2;
  p.out = out; p.cbuf = cbuf;

  for (int d = 0; d <= 19; ++d) {
    phase_kernel<<<832, 256, 0, stream>>>(p, d);
  }
  finalize_kernel<<<1, 256, 0, stream>>>(cbuf, out);
}

// Round 2
// 394.916 us; speedup vs baseline: 1.1979x; 1.1979x over previous
//
#include <hip/hip_runtime.h>
#include <math.h>

// NeuromorphicPrivacyNetwork: 3-layer LIF SNN, T=16, B=256, sizes 1024->2048->1024->512.
// Round-9: DE-PIPELINE. Key insight: the only recurrence is the elementwise LIF state;
// layer inputs are re-presented (L0) or fully known once the previous layer's whole
// spike train is computed. So:
//   - L0: all 16 steps in ONE dispatch (V/refractory in registers) -> sp0[16][256][2048]
//   - GEMM1: batched CUR1[t] = sp0[t] @ W1^T for all t = one 4096x1024x2048 bf16 GEMM
//   - L1: all 16 steps in ONE dispatch -> sp1[16][256][1024]
//   - GEMM2: one 4096x512x1024 bf16 GEMM
//   - L2: all 16 steps in ONE dispatch (+ out at t=16)
// 9 dispatches total (was 24 x ~19us, mostly launch/drain overhead).
// Cost buckets: pure stores (no accumulation across dispatches), disjoint ranges:
//   L0 [0,512), L1 [512,768), L2 [768,896). Spikes bf16 {0,1}; W1/W2 bf16; CUR fp32.

#define T_STEPS 16

typedef short short8 __attribute__((ext_vector_type(8)));
typedef float floatx4 __attribute__((ext_vector_type(4)));

__device__ inline ushort f2bf(float x) {
  unsigned int u = __float_as_uint(x);
  unsigned int r = (u + 0x7FFFu + ((u >> 16) & 1u)) >> 16;
  return (ushort)r;
}
__device__ inline float bf2f(ushort h) {
  return __uint_as_float(((unsigned int)h) << 16);
}
__device__ inline floatx4 mfma16(short8 a, short8 b, floatx4 c) {
  return __builtin_amdgcn_mfma_f32_16x16x32_bf16(a, b, c, 0, 0, 0);
}

// stage 16 fp32 -> hi/lo bf16 pairs into LDS (base0 setup GEMM only)
__device__ inline void stage_split16(const float* __restrict__ src, ushort* dsth, ushort* dstl) {
  float fv[16];
  #pragma unroll
  for (int i = 0; i < 4; ++i) *(float4*)&fv[4 * i] = *(const float4*)(src + 4 * i);
  unsigned int ph[8], pl[8];
  #pragma unroll
  for (int i = 0; i < 8; ++i) {
    ushort h0 = f2bf(fv[2 * i]);
    ushort l0 = f2bf(fv[2 * i] - bf2f(h0));
    ushort h1 = f2bf(fv[2 * i + 1]);
    ushort l1 = f2bf(fv[2 * i + 1] - bf2f(h1));
    ph[i] = (unsigned int)h0 | ((unsigned int)h1 << 16);
    pl[i] = (unsigned int)l0 | ((unsigned int)l1 << 16);
  }
  *(uint4*)dsth       = make_uint4(ph[0], ph[1], ph[2], ph[3]);
  *(uint4*)(dsth + 8) = make_uint4(ph[4], ph[5], ph[6], ph[7]);
  *(uint4*)dstl       = make_uint4(pl[0], pl[1], pl[2], pl[3]);
  *(uint4*)(dstl + 8) = make_uint4(pl[4], pl[5], pl[6], pl[7]);
}

// block-reduce then STORE into this block's private bucket (written exactly once).
__device__ inline void cost_store_bucket(float csum, int cnt, float2* __restrict__ cbuf,
                                         int bucket_base) {
  #pragma unroll
  for (int off = 32; off > 0; off >>= 1) {
    csum += __shfl_down(csum, off);
    cnt  += __shfl_down(cnt, off);
  }
  __shared__ float sc[4];
  __shared__ int   si[4];
  int wid = threadIdx.x >> 6;
  if ((threadIdx.x & 63) == 0) { sc[wid] = csum; si[wid] = cnt; }
  __syncthreads();
  if (threadIdx.x == 0) {
    float c = sc[0] + sc[1] + sc[2] + sc[3];
    int   k = si[0] + si[1] + si[2] + si[3];
    float2 v;
    v.x = c * 0.01f;             // per-spike cost = 0.1 * fac/10 * wn = 0.01*fac*wn
    v.y = (float)k;
    cbuf[bucket_base + blockIdx.x] = v;
  }
}

// ---------------- weight row norms ----------------

__global__ __launch_bounds__(64) void wnorm_kernel(const float* __restrict__ w0,
                                                   const float* __restrict__ w1,
                                                   const float* __restrict__ w2,
                                                   float* __restrict__ wn) {
  int r = blockIdx.x;  // 0..3583
  const float* row; int K;
  if (r < 2048)      { row = w0 + (size_t)r * 1024;          K = 1024; }
  else if (r < 3072) { row = w1 + (size_t)(r - 2048) * 2048; K = 2048; }
  else               { row = w2 + (size_t)(r - 3072) * 1024; K = 1024; }
  float ss = 0.f;
  for (int k = threadIdx.x; k < K; k += 64) { float x = row[k]; ss += x * x; }
  #pragma unroll
  for (int off = 32; off > 0; off >>= 1) ss += __shfl_down(ss, off);
  if (threadIdx.x == 0) wn[r] = sqrtf(ss);
}

// ---------------- convert W1,W2 -> bf16 ----------------

__global__ __launch_bounds__(256) void convert_w_kernel(const float* __restrict__ w1,
                                                        const float* __restrict__ w2,
                                                        ushort* __restrict__ w1b,
                                                        ushort* __restrict__ w2b) {
  int i = (blockIdx.x * 256 + threadIdx.x) * 8;   // 1280 blocks -> 2621440 elems
  const float* src; ushort* dst;
  if (i < 2097152) { src = w1 + i; dst = w1b + i; }
  else             { src = w2 + (i - 2097152); dst = w2b + (i - 2097152); }
  float4 a = *(const float4*)src;
  float4 b = *(const float4*)(src + 4);
  unsigned int p0 = (unsigned int)f2bf(a.x) | ((unsigned int)f2bf(a.y) << 16);
  unsigned int p1 = (unsigned int)f2bf(a.z) | ((unsigned int)f2bf(a.w) << 16);
  unsigned int p2 = (unsigned int)f2bf(b.x) | ((unsigned int)f2bf(b.y) << 16);
  unsigned int p3 = (unsigned int)f2bf(b.z) | ((unsigned int)f2bf(b.w) << 16);
  *(uint4*)dst = make_uint4(p0, p1, p2, p3);
}

// ---------------- base0 = inputs @ w0^T via split MFMA (one-time) ----------------

__global__ __launch_bounds__(256) void base0_mfma_kernel(const float* __restrict__ A,  // [256][1024]
                                                         const float* __restrict__ W,  // [2048][1024]
                                                         float* __restrict__ C) {      // [256][2048]
  __shared__ ushort Ah[64][72], Al[64][72], Bh[64][72], Bl[64][72];
  const int tid = threadIdx.x;
  const int m0 = blockIdx.x * 64;
  const int n0 = blockIdx.y * 64;
  const int lane = tid & 63, wv = tid >> 6;
  const int wm = wv & 1, wn2 = wv >> 1;
  const int l15 = lane & 15, quad = lane >> 4;
  const int sr = tid >> 2, scol = (tid & 3) * 16;

  floatx4 acc[2][2];
  #pragma unroll
  for (int i = 0; i < 2; ++i)
    #pragma unroll
    for (int j = 0; j < 2; ++j) acc[i][j] = (floatx4){0.f, 0.f, 0.f, 0.f};

  for (int k0 = 0; k0 < 1024; k0 += 64) {
    stage_split16(A + (size_t)(m0 + sr) * 1024 + k0 + scol, &Ah[sr][scol], &Al[sr][scol]);
    stage_split16(W + (size_t)(n0 + sr) * 1024 + k0 + scol, &Bh[sr][scol], &Bl[sr][scol]);
    __syncthreads();
    #pragma unroll
    for (int ks = 0; ks < 2; ++ks) {
      short8 ah[2], al[2], bh[2], bl[2];
      #pragma unroll
      for (int s = 0; s < 2; ++s) {
        ah[s] = *(const short8*)&Ah[32 * wm + 16 * s + l15][ks * 32 + quad * 8];
        al[s] = *(const short8*)&Al[32 * wm + 16 * s + l15][ks * 32 + quad * 8];
        bh[s] = *(const short8*)&Bh[32 * wn2 + 16 * s + l15][ks * 32 + quad * 8];
        bl[s] = *(const short8*)&Bl[32 * wn2 + 16 * s + l15][ks * 32 + quad * 8];
      }
      #pragma unroll
      for (int sm = 0; sm < 2; ++sm)
        #pragma unroll
        for (int sn = 0; sn < 2; ++sn) {
          acc[sm][sn] = mfma16(ah[sm], bh[sn], acc[sm][sn]);
          acc[sm][sn] = mfma16(ah[sm], bl[sn], acc[sm][sn]);
          acc[sm][sn] = mfma16(al[sm], bh[sn], acc[sm][sn]);
        }
    }
    __syncthreads();
  }
  #pragma unroll
  for (int sm = 0; sm < 2; ++sm)
    #pragma unroll
    for (int sn = 0; sn < 2; ++sn)
      #pragma unroll
      for (int r = 0; r < 4; ++r) {
        int m = m0 + 32 * wm + 16 * sm + quad * 4 + r;
        int n = n0 + 32 * wn2 + 16 * sn + l15;
        C[(size_t)m * 2048 + n] = acc[sm][sn][r];
      }
}

// ---------------- batched full-K GEMM: C[4096][N] = A[4096][K] @ W[N][K]^T ----------------

template<int K>
__device__ inline void ld_frags(const ushort* __restrict__ Abase,
                                const ushort* __restrict__ Wbase,
                                int l15, int k0, uint4 fa[2][2], uint4 fb[2][2]) {
  #pragma unroll
  for (int ks = 0; ks < 2; ++ks)
    #pragma unroll
    for (int s = 0; s < 2; ++s) {
      fa[ks][s] = *(const uint4*)(Abase + (size_t)(16 * s + l15) * K + k0 + ks * 32);
      fb[ks][s] = *(const uint4*)(Wbase + (size_t)(16 * s + l15) * K + k0 + ks * 32);
    }
}

template<int K, int N>
__global__ __launch_bounds__(256, 4) void gemm_full_kernel(const ushort* __restrict__ A,
                                                           const ushort* __restrict__ W,
                                                           float* __restrict__ C) {
  constexpr int NT = N / 64;          // n-tiles; grid = (4096/64)*NT, mt-major
  const int bid = blockIdx.x;
  const int m0 = (bid / NT) * 64;
  const int n0 = (bid % NT) * 64;
  const int tid = threadIdx.x;
  const int lane = tid & 63, wv = tid >> 6;
  const int wm = wv & 1, wn2 = wv >> 1;
  const int l15 = lane & 15, quad = lane >> 4;

  const ushort* Abase = A + (size_t)(m0 + 32 * wm) * K + quad * 8;
  const ushort* Wbase = W + (size_t)(n0 + 32 * wn2) * K + quad * 8;

  floatx4 acc[2][2];
  #pragma unroll
  for (int i = 0; i < 2; ++i)
    #pragma unroll
    for (int j = 0; j < 2; ++j) acc[i][j] = (floatx4){0.f, 0.f, 0.f, 0.f};

  uint4 fa[2][2], fb[2][2];
  ld_frags<K>(Abase, Wbase, l15, 0, fa, fb);
  for (int k0 = 0; k0 < K; k0 += 64) {
    uint4 na[2][2], nb[2][2];
    if (k0 + 64 < K) ld_frags<K>(Abase, Wbase, l15, k0 + 64, na, nb);
    #pragma unroll
    for (int ks = 0; ks < 2; ++ks)
      #pragma unroll
      for (int sm = 0; sm < 2; ++sm)
        #pragma unroll
        for (int sn = 0; sn < 2; ++sn)
          acc[sm][sn] = mfma16(*(const short8*)&fa[ks][sm], *(const short8*)&fb[ks][sn], acc[sm][sn]);
    #pragma unroll
    for (int ks = 0; ks < 2; ++ks)
      #pragma unroll
      for (int s = 0; s < 2; ++s) { fa[ks][s] = na[ks][s]; fb[ks][s] = nb[ks][s]; }
  }

  #pragma unroll
  for (int sm = 0; sm < 2; ++sm)
    #pragma unroll
    for (int sn = 0; sn < 2; ++sn)
      #pragma unroll
      for (int r = 0; r < 4; ++r) {
        int m = m0 + 32 * wm + 16 * sm + quad * 4 + r;
        int n = n0 + 32 * wn2 + 16 * sn + l15;
        C[(size_t)m * N + n] = acc[sm][sn][r];
      }
}

// ---------------- L0 LIF: all 16 steps, state in registers ----------------
// 512 blocks x 256 threads x 4 elems = 524288 elems of (b, n0)

__global__ __launch_bounds__(256) void l0_lif_kernel(const float* __restrict__ base0,
                                                     const float* __restrict__ cn0,
                                                     const float* __restrict__ tn0,
                                                     const float* __restrict__ th0,
                                                     const float* __restrict__ wn0,
                                                     ushort* __restrict__ sp0,
                                                     float2* __restrict__ cbuf) {
  const int e = (blockIdx.x * 256 + threadIdx.x) * 4;
  const int n = e & 2047;
  float4 bb  = *(const float4*)(base0 + e);
  float4 th4 = *(const float4*)(th0 + n);
  float4 wn4 = *(const float4*)(wn0 + n);
  float bbv[4] = {bb.x, bb.y, bb.z, bb.w};
  float thv[4] = {th4.x, th4.y, th4.z, th4.w};
  float wnq[4] = {wn4.x, wn4.y, wn4.z, wn4.w};
  float V[4] = {0.f, 0.f, 0.f, 0.f};
  bool prev[4] = {false, false, false, false};
  float csum = 0.f; int cnt = 0;
  #pragma unroll 2
  for (int t = 1; t <= T_STEPS; ++t) {
    size_t off = (size_t)(t - 1) * 524288 + e;
    float4 c4 = *(const float4*)(cn0 + off);
    float4 t4 = *(const float4*)(tn0 + off);
    float cnv[4] = {c4.x, c4.y, c4.z, c4.w};
    float tnv[4] = {t4.x, t4.y, t4.z, t4.w};
    float f = (t <= 7) ? 10.f : (float)(17 - t);
    ushort sout[4];
    #pragma unroll
    for (int j = 0; j < 4; ++j) {
      float cur = bbv[j] + cnv[j] * (0.05f * wnq[j]);
      float Vn = prev[j] ? V[j] : (0.95f * V[j] + cur);
      float thr = thv[j] + tnv[j] * 0.1f;
      bool sp = (!prev[j]) && (Vn > thr);
      V[j] = sp ? 0.f : Vn;
      sout[j] = sp ? (ushort)0x3F80 : (ushort)0;
      prev[j] = sp;
      if (sp) { csum += wnq[j] * f; cnt++; }
    }
    ushort4 sq; sq.x = sout[0]; sq.y = sout[1]; sq.z = sout[2]; sq.w = sout[3];
    *(ushort4*)(sp0 + off) = sq;
  }
  cost_store_bucket(csum, cnt, cbuf, 0);
}

// ---------------- L1/L2 LIF: all 16 steps from CUR, state in registers ----------------

template<int N, bool LAST>
__global__ __launch_bounds__(256) void lif_seq_kernel(const float* __restrict__ CUR,
                                                      const float* __restrict__ cn,
                                                      const float* __restrict__ tn,
                                                      const float* __restrict__ th,
                                                      const float* __restrict__ wnv,
                                                      ushort* __restrict__ spout,
                                                      float* __restrict__ outF,
                                                      float2* __restrict__ cbuf,
                                                      int bucket_base) {
  constexpr int SZ = 256 * N;
  const int e = (blockIdx.x * 256 + threadIdx.x) * 4;
  const int n = e & (N - 1);
  float4 th4 = *(const float4*)(th + n);
  float4 wn4 = *(const float4*)(wnv + n);
  float thv[4] = {th4.x, th4.y, th4.z, th4.w};
  float wnq[4] = {wn4.x, wn4.y, wn4.z, wn4.w};
  float V[4] = {0.f, 0.f, 0.f, 0.f};
  bool prev[4] = {false, false, false, false};
  float csum = 0.f; int cnt = 0;
  #pragma unroll 2
  for (int t = 1; t <= T_STEPS; ++t) {
    size_t off = (size_t)(t - 1) * SZ + e;
    float4 a4 = *(const float4*)(CUR + off);
    float4 c4 = *(const float4*)(cn + off);
    float4 t4 = *(const float4*)(tn + off);
    float av[4]  = {a4.x, a4.y, a4.z, a4.w};
    float cnv[4] = {c4.x, c4.y, c4.z, c4.w};
    float tnv[4] = {t4.x, t4.y, t4.z, t4.w};
    float f = (t <= 7) ? 10.f : (float)(17 - t);
    ushort sout[4];
    #pragma unroll
    for (int j = 0; j < 4; ++j) {
      float cur = av[j] + cnv[j] * (0.05f * wnq[j]);
      float Vn = prev[j] ? V[j] : (0.95f * V[j] + cur);
      float thr = thv[j] + tnv[j] * 0.1f;
      bool sp = (!prev[j]) && (Vn > thr);
      V[j] = sp ? 0.f : Vn;
      sout[j] = sp ? (ushort)0x3F80 : (ushort)0;
      prev[j] = sp;
      if (sp) { csum += wnq[j] * f; cnt++; }
    }
    if (!LAST) {
      ushort4 sq; sq.x = sout[0]; sq.y = sout[1]; sq.z = sout[2]; sq.w = sout[3];
      *(ushort4*)(spout + off) = sq;
    } else if (t == T_STEPS) {
      *(float4*)(outF + e) = make_float4(sout[0] ? 1.f : 0.f, sout[1] ? 1.f : 0.f,
                                         sout[2] ? 1.f : 0.f, sout[3] ? 1.f : 0.f);
    }
  }
  cost_store_bucket(csum, cnt, cbuf, bucket_base);
}

// ---------------- finalize: reduce 896 buckets -> cost, entropy ----------------

__global__ __launch_bounds__(256) void finalize_kernel(const float2* __restrict__ cbuf,
                                                       float* __restrict__ out) {
  float c = 0.f, k = 0.f;
  for (int i = threadIdx.x; i < 896; i += 256) {
    float2 v = cbuf[i];
    c += v.x; k += v.y;
  }
  #pragma unroll
  for (int off = 32; off > 0; off >>= 1) {
    c += __shfl_down(c, off);
    k += __shfl_down(k, off);
  }
  __shared__ float sc[4], sk[4];
  int wid = threadIdx.x >> 6;
  if ((threadIdx.x & 63) == 0) { sc[wid] = c; sk[wid] = k; }
  __syncthreads();
  if (threadIdx.x == 0) {
    float cost = sc[0] + sc[1] + sc[2] + sc[3];
    float tot  = sk[0] + sk[1] + sk[2] + sk[3];
    float p1 = tot / 14680064.f;   // T*B*(2048+1024+512)
    float p0 = 1.f - p1;
    float ent = -(p1 * log2f(p1 + 1e-12f) + p0 * log2f(p0 + 1e-12f));
    out[131072] = cost;
    out[131073] = ent;
  }
}

// ---------------- launch ----------------

extern "C" void kernel_launch(void* const* d_in, const int* in_sizes, int n_in,
                              void* d_out, int out_size, void* d_ws, size_t ws_size,
                              hipStream_t stream) {
  const float* inputs = (const float*)d_in[0];
  const float* w0  = (const float*)d_in[1];
  const float* th0 = (const float*)d_in[2];
  const float* cn0 = (const float*)d_in[3];
  const float* tn0 = (const float*)d_in[4];
  const float* w1  = (const float*)d_in[5];
  const float* th1 = (const float*)d_in[6];
  const float* cn1 = (const float*)d_in[7];
  const float* tn1 = (const float*)d_in[8];
  const float* w2  = (const float*)d_in[9];
  const float* th2 = (const float*)d_in[10];
  const float* cn2 = (const float*)d_in[11];
  const float* tn2 = (const float*)d_in[12];
  float* out = (float*)d_out;
  float* ws  = (float*)d_ws;

  // workspace layout (float slots), total ~14.42M floats ~= 58 MB
  float* wn    = ws;                        // 3584 (pad 4096)
  float* base0 = ws + 4096;                 // 524288 fp32 [256][2048]
  float* cur1  = base0 + 524288;            // 4194304 fp32 [16][256][1024]
  float* cur2  = cur1 + 4194304;            // 2097152 fp32 [16][256][512]
  ushort* w1b  = (ushort*)(cur2 + 2097152); // 2097152 ushort [1024][2048]
  ushort* w2b  = w1b + 2097152;             // 524288 ushort [512][1024]
  ushort* sp0  = w2b + 524288;              // 8388608 ushort [16][256][2048]
  ushort* sp1  = sp0 + 8388608;             // 4194304 ushort [16][256][1024]
  float2* cbuf = (float2*)(sp1 + 4194304);  // 896 float2

  wnorm_kernel<<<3584, 64, 0, stream>>>(w0, w1, w2, wn);
  convert_w_kernel<<<1280, 256, 0, stream>>>(w1, w2, w1b, w2b);
  base0_mfma_kernel<<<dim3(4, 32), 256, 0, stream>>>(inputs, w0, base0);

  // L0: all 16 steps -> sp0, buckets [0,512)
  l0_lif_kernel<<<512, 256, 0, stream>>>(base0, cn0, tn0, th0, wn, sp0, cbuf);

  // GEMM1: cur1[4096][1024] = sp0[4096][2048] @ w1b[1024][2048]^T
  gemm_full_kernel<2048, 1024><<<(4096 / 64) * (1024 / 64), 256, 0, stream>>>(sp0, w1b, cur1);

  // L1: all 16 steps -> sp1, buckets [512,768)
  lif_seq_kernel<1024, false><<<256, 256, 0, stream>>>(cur1, cn1, tn1, th1, wn + 2048,
                                                       sp1, nullptr, cbuf, 512);

  // GEMM2: cur2[4096][512] = sp1[4096][1024] @ w2b[512][1024]^T
  gemm_full_kernel<1024, 512><<<(4096 / 64) * (512 / 64), 256, 0, stream>>>(sp1, w2b, cur2);

  // L2: all 16 steps -> out (t=16), buckets [768,896)
  lif_seq_kernel<512, true><<<128, 256, 0, stream>>>(cur2, cn2, tn2, th2, wn + 3072,
                                                     nullptr, out, cbuf, 768);

  finalize_kernel<<<1, 256, 0, stream>>>(cbuf, out);
}

// Round 3
// 359.545 us; speedup vs baseline: 1.3157x; 1.0984x over previous
//
#include <hip/hip_runtime.h>
#include <math.h>

// NeuromorphicPrivacyNetwork: 3-layer LIF SNN, T=16, B=256, sizes 1024->2048->1024->512.
// Round-10: LDS-staged batched GEMMs. Round-9's de-pipeline exposed the real bottleneck:
// gemm_full (direct-global fragment loads) was latency-bound (MfmaUtil 5.4%, VALUBusy 3%,
// HBM 9%) at 119us. Replace with 128x128-tile, BK=64, 4-wave, double-buffered LDS GEMM:
//   - T14 async-stage: global loads for tile k+1 issued BEFORE the MFMA block on tile k,
//     ds_write after (latency hidden under compute); one barrier per K-step.
//   - T2 XOR swizzle (16B-slot ^ (row&7)) on both ds_write and ds_read sides: kills the
//     128B-stride column bank conflict without padding.
//   - per wave: 64x64 output = 4x4 16x16x32 frags; 16 ds_read_b128 + 32 MFMA per K-step.
// Everything else (LIF sequencers, base0, cost buckets) unchanged from round-9 (passed).

#define T_STEPS 16

typedef short short8 __attribute__((ext_vector_type(8)));
typedef float floatx4 __attribute__((ext_vector_type(4)));

__device__ inline ushort f2bf(float x) {
  unsigned int u = __float_as_uint(x);
  unsigned int r = (u + 0x7FFFu + ((u >> 16) & 1u)) >> 16;
  return (ushort)r;
}
__device__ inline float bf2f(ushort h) {
  return __uint_as_float(((unsigned int)h) << 16);
}
__device__ inline floatx4 mfma16(short8 a, short8 b, floatx4 c) {
  return __builtin_amdgcn_mfma_f32_16x16x32_bf16(a, b, c, 0, 0, 0);
}

// stage 16 fp32 -> hi/lo bf16 pairs into LDS (base0 setup GEMM only)
__device__ inline void stage_split16(const float* __restrict__ src, ushort* dsth, ushort* dstl) {
  float fv[16];
  #pragma unroll
  for (int i = 0; i < 4; ++i) *(float4*)&fv[4 * i] = *(const float4*)(src + 4 * i);
  unsigned int ph[8], pl[8];
  #pragma unroll
  for (int i = 0; i < 8; ++i) {
    ushort h0 = f2bf(fv[2 * i]);
    ushort l0 = f2bf(fv[2 * i] - bf2f(h0));
    ushort h1 = f2bf(fv[2 * i + 1]);
    ushort l1 = f2bf(fv[2 * i + 1] - bf2f(h1));
    ph[i] = (unsigned int)h0 | ((unsigned int)h1 << 16);
    pl[i] = (unsigned int)l0 | ((unsigned int)l1 << 16);
  }
  *(uint4*)dsth       = make_uint4(ph[0], ph[1], ph[2], ph[3]);
  *(uint4*)(dsth + 8) = make_uint4(ph[4], ph[5], ph[6], ph[7]);
  *(uint4*)dstl       = make_uint4(pl[0], pl[1], pl[2], pl[3]);
  *(uint4*)(dstl + 8) = make_uint4(pl[4], pl[5], pl[6], pl[7]);
}

// block-reduce then STORE into this block's private bucket (written exactly once).
__device__ inline void cost_store_bucket(float csum, int cnt, float2* __restrict__ cbuf,
                                         int bucket_base) {
  #pragma unroll
  for (int off = 32; off > 0; off >>= 1) {
    csum += __shfl_down(csum, off);
    cnt  += __shfl_down(cnt, off);
  }
  __shared__ float sc[4];
  __shared__ int   si[4];
  int wid = threadIdx.x >> 6;
  if ((threadIdx.x & 63) == 0) { sc[wid] = csum; si[wid] = cnt; }
  __syncthreads();
  if (threadIdx.x == 0) {
    float c = sc[0] + sc[1] + sc[2] + sc[3];
    int   k = si[0] + si[1] + si[2] + si[3];
    float2 v;
    v.x = c * 0.01f;             // per-spike cost = 0.1 * fac/10 * wn = 0.01*fac*wn
    v.y = (float)k;
    cbuf[bucket_base + blockIdx.x] = v;
  }
}

// ---------------- weight row norms ----------------

__global__ __launch_bounds__(64) void wnorm_kernel(const float* __restrict__ w0,
                                                   const float* __restrict__ w1,
                                                   const float* __restrict__ w2,
                                                   float* __restrict__ wn) {
  int r = blockIdx.x;  // 0..3583
  const float* row; int K;
  if (r < 2048)      { row = w0 + (size_t)r * 1024;          K = 1024; }
  else if (r < 3072) { row = w1 + (size_t)(r - 2048) * 2048; K = 2048; }
  else               { row = w2 + (size_t)(r - 3072) * 1024; K = 1024; }
  float ss = 0.f;
  for (int k = threadIdx.x; k < K; k += 64) { float x = row[k]; ss += x * x; }
  #pragma unroll
  for (int off = 32; off > 0; off >>= 1) ss += __shfl_down(ss, off);
  if (threadIdx.x == 0) wn[r] = sqrtf(ss);
}

// ---------------- convert W1,W2 -> bf16 ----------------

__global__ __launch_bounds__(256) void convert_w_kernel(const float* __restrict__ w1,
                                                        const float* __restrict__ w2,
                                                        ushort* __restrict__ w1b,
                                                        ushort* __restrict__ w2b) {
  int i = (blockIdx.x * 256 + threadIdx.x) * 8;   // 1280 blocks -> 2621440 elems
  const float* src; ushort* dst;
  if (i < 2097152) { src = w1 + i; dst = w1b + i; }
  else             { src = w2 + (i - 2097152); dst = w2b + (i - 2097152); }
  float4 a = *(const float4*)src;
  float4 b = *(const float4*)(src + 4);
  unsigned int p0 = (unsigned int)f2bf(a.x) | ((unsigned int)f2bf(a.y) << 16);
  unsigned int p1 = (unsigned int)f2bf(a.z) | ((unsigned int)f2bf(a.w) << 16);
  unsigned int p2 = (unsigned int)f2bf(b.x) | ((unsigned int)f2bf(b.y) << 16);
  unsigned int p3 = (unsigned int)f2bf(b.z) | ((unsigned int)f2bf(b.w) << 16);
  *(uint4*)dst = make_uint4(p0, p1, p2, p3);
}

// ---------------- base0 = inputs @ w0^T via split MFMA (one-time) ----------------

__global__ __launch_bounds__(256) void base0_mfma_kernel(const float* __restrict__ A,  // [256][1024]
                                                         const float* __restrict__ W,  // [2048][1024]
                                                         float* __restrict__ C) {      // [256][2048]
  __shared__ ushort Ah[64][72], Al[64][72], Bh[64][72], Bl[64][72];
  const int tid = threadIdx.x;
  const int m0 = blockIdx.x * 64;
  const int n0 = blockIdx.y * 64;
  const int lane = tid & 63, wv = tid >> 6;
  const int wm = wv & 1, wn2 = wv >> 1;
  const int l15 = lane & 15, quad = lane >> 4;
  const int sr = tid >> 2, scol = (tid & 3) * 16;

  floatx4 acc[2][2];
  #pragma unroll
  for (int i = 0; i < 2; ++i)
    #pragma unroll
    for (int j = 0; j < 2; ++j) acc[i][j] = (floatx4){0.f, 0.f, 0.f, 0.f};

  for (int k0 = 0; k0 < 1024; k0 += 64) {
    stage_split16(A + (size_t)(m0 + sr) * 1024 + k0 + scol, &Ah[sr][scol], &Al[sr][scol]);
    stage_split16(W + (size_t)(n0 + sr) * 1024 + k0 + scol, &Bh[sr][scol], &Bl[sr][scol]);
    __syncthreads();
    #pragma unroll
    for (int ks = 0; ks < 2; ++ks) {
      short8 ah[2], al[2], bh[2], bl[2];
      #pragma unroll
      for (int s = 0; s < 2; ++s) {
        ah[s] = *(const short8*)&Ah[32 * wm + 16 * s + l15][ks * 32 + quad * 8];
        al[s] = *(const short8*)&Al[32 * wm + 16 * s + l15][ks * 32 + quad * 8];
        bh[s] = *(const short8*)&Bh[32 * wn2 + 16 * s + l15][ks * 32 + quad * 8];
        bl[s] = *(const short8*)&Bl[32 * wn2 + 16 * s + l15][ks * 32 + quad * 8];
      }
      #pragma unroll
      for (int sm = 0; sm < 2; ++sm)
        #pragma unroll
        for (int sn = 0; sn < 2; ++sn) {
          acc[sm][sn] = mfma16(ah[sm], bh[sn], acc[sm][sn]);
          acc[sm][sn] = mfma16(ah[sm], bl[sn], acc[sm][sn]);
          acc[sm][sn] = mfma16(al[sm], bh[sn], acc[sm][sn]);
        }
    }
    __syncthreads();
  }
  #pragma unroll
  for (int sm = 0; sm < 2; ++sm)
    #pragma unroll
    for (int sn = 0; sn < 2; ++sn)
      #pragma unroll
      for (int r = 0; r < 4; ++r) {
        int m = m0 + 32 * wm + 16 * sm + quad * 4 + r;
        int n = n0 + 32 * wn2 + 16 * sn + l15;
        C[(size_t)m * 2048 + n] = acc[sm][sn][r];
      }
}

// ---------------- LDS-staged batched GEMM: C[4096][N] = A[4096][K] @ W[N][K]^T --------
// 128x128 tile, BK=64, 4 waves (each 64x64 = 4x4 16x16x32 frags), double-buffered LDS,
// XOR-swizzled 16B slots, async-stage split (loads early, ds_write late), 1 barrier/step.

template<int K, int N>
__global__ __launch_bounds__(256) void gemm_lds_kernel(const ushort* __restrict__ A,
                                                       const ushort* __restrict__ W,
                                                       float* __restrict__ C) {
  __shared__ __attribute__((aligned(16))) ushort As[2][128 * 64];
  __shared__ __attribute__((aligned(16))) ushort Bs[2][128 * 64];
  constexpr int NT = N / 128;
  const int bid = blockIdx.x;
  const int m0 = (bid / NT) * 128;
  const int n0 = (bid % NT) * 128;
  const int tid = threadIdx.x;
  const int lane = tid & 63, wv = tid >> 6;
  const int wm = wv & 1, wn2 = wv >> 1;
  const int l15 = lane & 15, quad = lane >> 4;

  // staging map: per pass p (0..3): row = p*32 + tid/8, 16B slot = tid%8
  const int srow = tid >> 3;
  const int sslot = tid & 7;
  const ushort* Ab = A + (size_t)m0 * K;
  const ushort* Wb = W + (size_t)n0 * K;

  floatx4 acc[4][4];
  #pragma unroll
  for (int i = 0; i < 4; ++i)
    #pragma unroll
    for (int j = 0; j < 4; ++j) acc[i][j] = (floatx4){0.f, 0.f, 0.f, 0.f};

  uint4 ra[4], rb[4];

  auto load_regs = [&](int k0) {
    #pragma unroll
    for (int p = 0; p < 4; ++p) {
      int row = p * 32 + srow;
      ra[p] = *(const uint4*)(Ab + (size_t)row * K + k0 + sslot * 8);
      rb[p] = *(const uint4*)(Wb + (size_t)row * K + k0 + sslot * 8);
    }
  };
  auto store_lds = [&](int buf) {
    #pragma unroll
    for (int p = 0; p < 4; ++p) {
      int row = p * 32 + srow;
      int sw = ((sslot ^ (row & 7)) << 3);
      *(uint4*)&As[buf][row * 64 + sw] = ra[p];
      *(uint4*)&Bs[buf][row * 64 + sw] = rb[p];
    }
  };
  auto compute = [&](int buf) {
    #pragma unroll
    for (int ks = 0; ks < 2; ++ks) {
      short8 af[4], bf[4];
      #pragma unroll
      for (int s = 0; s < 4; ++s) {
        int arow = wm * 64 + s * 16 + l15;
        int brow = wn2 * 64 + s * 16 + l15;
        af[s] = *(const short8*)&As[buf][arow * 64 + (((ks * 4 + quad) ^ (arow & 7)) << 3)];
        bf[s] = *(const short8*)&Bs[buf][brow * 64 + (((ks * 4 + quad) ^ (brow & 7)) << 3)];
      }
      #pragma unroll
      for (int sm = 0; sm < 4; ++sm)
        #pragma unroll
        for (int sn = 0; sn < 4; ++sn)
          acc[sm][sn] = mfma16(af[sm], bf[sn], acc[sm][sn]);
    }
  };

  load_regs(0);
  store_lds(0);
  __syncthreads();
  constexpr int NSTEP = K / 64;
  for (int kk = 0; kk < NSTEP; ++kk) {
    int buf = kk & 1;
    if (kk + 1 < NSTEP) load_regs((kk + 1) * 64);   // issue early (hidden under MFMA)
    compute(buf);
    if (kk + 1 < NSTEP) store_lds(buf ^ 1);         // write late (after compute)
    __syncthreads();
  }

  #pragma unroll
  for (int sm = 0; sm < 4; ++sm)
    #pragma unroll
    for (int sn = 0; sn < 4; ++sn)
      #pragma unroll
      for (int r = 0; r < 4; ++r) {
        int m = m0 + wm * 64 + sm * 16 + quad * 4 + r;
        int n = n0 + wn2 * 64 + sn * 16 + l15;
        C[(size_t)m * N + n] = acc[sm][sn][r];
      }
}

// ---------------- L0 LIF: all 16 steps, state in registers ----------------
// 512 blocks x 256 threads x 4 elems = 524288 elems of (b, n0)

__global__ __launch_bounds__(256) void l0_lif_kernel(const float* __restrict__ base0,
                                                     const float* __restrict__ cn0,
                                                     const float* __restrict__ tn0,
                                                     const float* __restrict__ th0,
                                                     const float* __restrict__ wn0,
                                                     ushort* __restrict__ sp0,
                                                     float2* __restrict__ cbuf) {
  const int e = (blockIdx.x * 256 + threadIdx.x) * 4;
  const int n = e & 2047;
  float4 bb  = *(const float4*)(base0 + e);
  float4 th4 = *(const float4*)(th0 + n);
  float4 wn4 = *(const float4*)(wn0 + n);
  float bbv[4] = {bb.x, bb.y, bb.z, bb.w};
  float thv[4] = {th4.x, th4.y, th4.z, th4.w};
  float wnq[4] = {wn4.x, wn4.y, wn4.z, wn4.w};
  float V[4] = {0.f, 0.f, 0.f, 0.f};
  bool prev[4] = {false, false, false, false};
  float csum = 0.f; int cnt = 0;
  #pragma unroll 2
  for (int t = 1; t <= T_STEPS; ++t) {
    size_t off = (size_t)(t - 1) * 524288 + e;
    float4 c4 = *(const float4*)(cn0 + off);
    float4 t4 = *(const float4*)(tn0 + off);
    float cnv[4] = {c4.x, c4.y, c4.z, c4.w};
    float tnv[4] = {t4.x, t4.y, t4.z, t4.w};
    float f = (t <= 7) ? 10.f : (float)(17 - t);
    ushort sout[4];
    #pragma unroll
    for (int j = 0; j < 4; ++j) {
      float cur = bbv[j] + cnv[j] * (0.05f * wnq[j]);
      float Vn = prev[j] ? V[j] : (0.95f * V[j] + cur);
      float thr = thv[j] + tnv[j] * 0.1f;
      bool sp = (!prev[j]) && (Vn > thr);
      V[j] = sp ? 0.f : Vn;
      sout[j] = sp ? (ushort)0x3F80 : (ushort)0;
      prev[j] = sp;
      if (sp) { csum += wnq[j] * f; cnt++; }
    }
    ushort4 sq; sq.x = sout[0]; sq.y = sout[1]; sq.z = sout[2]; sq.w = sout[3];
    *(ushort4*)(sp0 + off) = sq;
  }
  cost_store_bucket(csum, cnt, cbuf, 0);
}

// ---------------- L1/L2 LIF: all 16 steps from CUR, state in registers ----------------

template<int N, bool LAST>
__global__ __launch_bounds__(256) void lif_seq_kernel(const float* __restrict__ CUR,
                                                      const float* __restrict__ cn,
                                                      const float* __restrict__ tn,
                                                      const float* __restrict__ th,
                                                      const float* __restrict__ wnv,
                                                      ushort* __restrict__ spout,
                                                      float* __restrict__ outF,
                                                      float2* __restrict__ cbuf,
                                                      int bucket_base) {
  constexpr int SZ = 256 * N;
  const int e = (blockIdx.x * 256 + threadIdx.x) * 4;
  const int n = e & (N - 1);
  float4 th4 = *(const float4*)(th + n);
  float4 wn4 = *(const float4*)(wnv + n);
  float thv[4] = {th4.x, th4.y, th4.z, th4.w};
  float wnq[4] = {wn4.x, wn4.y, wn4.z, wn4.w};
  float V[4] = {0.f, 0.f, 0.f, 0.f};
  bool prev[4] = {false, false, false, false};
  float csum = 0.f; int cnt = 0;
  #pragma unroll 2
  for (int t = 1; t <= T_STEPS; ++t) {
    size_t off = (size_t)(t - 1) * SZ + e;
    float4 a4 = *(const float4*)(CUR + off);
    float4 c4 = *(const float4*)(cn + off);
    float4 t4 = *(const float4*)(tn + off);
    float av[4]  = {a4.x, a4.y, a4.z, a4.w};
    float cnv[4] = {c4.x, c4.y, c4.z, c4.w};
    float tnv[4] = {t4.x, t4.y, t4.z, t4.w};
    float f = (t <= 7) ? 10.f : (float)(17 - t);
    ushort sout[4];
    #pragma unroll
    for (int j = 0; j < 4; ++j) {
      float cur = av[j] + cnv[j] * (0.05f * wnq[j]);
      float Vn = prev[j] ? V[j] : (0.95f * V[j] + cur);
      float thr = thv[j] + tnv[j] * 0.1f;
      bool sp = (!prev[j]) && (Vn > thr);
      V[j] = sp ? 0.f : Vn;
      sout[j] = sp ? (ushort)0x3F80 : (ushort)0;
      prev[j] = sp;
      if (sp) { csum += wnq[j] * f; cnt++; }
    }
    if (!LAST) {
      ushort4 sq; sq.x = sout[0]; sq.y = sout[1]; sq.z = sout[2]; sq.w = sout[3];
      *(ushort4*)(spout + off) = sq;
    } else if (t == T_STEPS) {
      *(float4*)(outF + e) = make_float4(sout[0] ? 1.f : 0.f, sout[1] ? 1.f : 0.f,
                                         sout[2] ? 1.f : 0.f, sout[3] ? 1.f : 0.f);
    }
  }
  cost_store_bucket(csum, cnt, cbuf, bucket_base);
}

// ---------------- finalize: reduce 896 buckets -> cost, entropy ----------------

__global__ __launch_bounds__(256) void finalize_kernel(const float2* __restrict__ cbuf,
                                                       float* __restrict__ out) {
  float c = 0.f, k = 0.f;
  for (int i = threadIdx.x; i < 896; i += 256) {
    float2 v = cbuf[i];
    c += v.x; k += v.y;
  }
  #pragma unroll
  for (int off = 32; off > 0; off >>= 1) {
    c += __shfl_down(c, off);
    k += __shfl_down(k, off);
  }
  __shared__ float sc[4], sk[4];
  int wid = threadIdx.x >> 6;
  if ((threadIdx.x & 63) == 0) { sc[wid] = c; sk[wid] = k; }
  __syncthreads();
  if (threadIdx.x == 0) {
    float cost = sc[0] + sc[1] + sc[2] + sc[3];
    float tot  = sk[0] + sk[1] + sk[2] + sk[3];
    float p1 = tot / 14680064.f;   // T*B*(2048+1024+512)
    float p0 = 1.f - p1;
    float ent = -(p1 * log2f(p1 + 1e-12f) + p0 * log2f(p0 + 1e-12f));
    out[131072] = cost;
    out[131073] = ent;
  }
}

// ---------------- launch ----------------

extern "C" void kernel_launch(void* const* d_in, const int* in_sizes, int n_in,
                              void* d_out, int out_size, void* d_ws, size_t ws_size,
                              hipStream_t stream) {
  const float* inputs = (const float*)d_in[0];
  const float* w0  = (const float*)d_in[1];
  const float* th0 = (const float*)d_in[2];
  const float* cn0 = (const float*)d_in[3];
  const float* tn0 = (const float*)d_in[4];
  const float* w1  = (const float*)d_in[5];
  const float* th1 = (const float*)d_in[6];
  const float* cn1 = (const float*)d_in[7];
  const float* tn1 = (const float*)d_in[8];
  const float* w2  = (const float*)d_in[9];
  const float* th2 = (const float*)d_in[10];
  const float* cn2 = (const float*)d_in[11];
  const float* tn2 = (const float*)d_in[12];
  float* out = (float*)d_out;
  float* ws  = (float*)d_ws;

  // workspace layout (float slots), total ~14.42M floats ~= 58 MB
  float* wn    = ws;                        // 3584 (pad 4096)
  float* base0 = ws + 4096;                 // 524288 fp32 [256][2048]
  float* cur1  = base0 + 524288;            // 4194304 fp32 [16][256][1024]
  float* cur2  = cur1 + 4194304;            // 2097152 fp32 [16][256][512]
  ushort* w1b  = (ushort*)(cur2 + 2097152); // 2097152 ushort [1024][2048]
  ushort* w2b  = w1b + 2097152;             // 524288 ushort [512][1024]
  ushort* sp0  = w2b + 524288;              // 8388608 ushort [16][256][2048]
  ushort* sp1  = sp0 + 8388608;             // 4194304 ushort [16][256][1024]
  float2* cbuf = (float2*)(sp1 + 4194304);  // 896 float2

  wnorm_kernel<<<3584, 64, 0, stream>>>(w0, w1, w2, wn);
  convert_w_kernel<<<1280, 256, 0, stream>>>(w1, w2, w1b, w2b);
  base0_mfma_kernel<<<dim3(4, 32), 256, 0, stream>>>(inputs, w0, base0);

  // L0: all 16 steps -> sp0, buckets [0,512)
  l0_lif_kernel<<<512, 256, 0, stream>>>(base0, cn0, tn0, th0, wn, sp0, cbuf);

  // GEMM1: cur1[4096][1024] = sp0[4096][2048] @ w1b[1024][2048]^T  (256 blocks)
  gemm_lds_kernel<2048, 1024><<<(4096 / 128) * (1024 / 128), 256, 0, stream>>>(sp0, w1b, cur1);

  // L1: all 16 steps -> sp1, buckets [512,768)
  lif_seq_kernel<1024, false><<<256, 256, 0, stream>>>(cur1, cn1, tn1, th1, wn + 2048,
                                                       sp1, nullptr, cbuf, 512);

  // GEMM2: cur2[4096][512] = sp1[4096][1024] @ w2b[512][1024]^T  (128 blocks)
  gemm_lds_kernel<1024, 512><<<(4096 / 128) * (512 / 128), 256, 0, stream>>>(sp1, w2b, cur2);

  // L2: all 16 steps -> out (t=16), buckets [768,896)
  lif_seq_kernel<512, true><<<128, 256, 0, stream>>>(cur2, cn2, tn2, th2, wn + 3072,
                                                     nullptr, out, cbuf, 768);

  finalize_kernel<<<1, 256, 0, stream>>>(cbuf, out);
}

// Round 5
// 294.821 us; speedup vs baseline: 1.6046x; 1.2195x over previous
//
#include <hip/hip_runtime.h>
#include <math.h>

// NeuromorphicPrivacyNetwork: 3-layer LIF SNN, T=16, B=256, sizes 1024->2048->1024->512.
// Round-12: fix round-11's staging-coverage bug. One global_load_lds (16B/lane, 64 lanes)
// covers 1KB = 8 rows of the 128B-wide LDS tile; round-11 stepped r0 by 16 rows (h=0..1)
// so HALF the rows were never staged (absmax fail). Now h=0..3, r0 = wv*32 + h*8:
// 16 gload16 per matrix per K-step = all 128 rows. Design otherwise identical:
//   (a) K-split 2 on both GEMMs -> 512/256 blocks; LIF sums the two fp32 partials.
//   (b) global_load_lds staging, swizzle on the GLOBAL SOURCE (LDS dest linear);
//       read-side XOR unchanged (same involution: LDS[r][s]=G[r][s^(r&7)]).
//   (c) Bijective XCD-aware block swizzle (m-major chunks per XCD).
//   LDS 64KB (2 blocks/CU). P2 aliased onto sp0 region (dead by GEMM2).

#define T_STEPS 16

typedef short short8 __attribute__((ext_vector_type(8)));
typedef float floatx4 __attribute__((ext_vector_type(4)));

__device__ inline ushort f2bf(float x) {
  unsigned int u = __float_as_uint(x);
  unsigned int r = (u + 0x7FFFu + ((u >> 16) & 1u)) >> 16;
  return (ushort)r;
}
__device__ inline float bf2f(ushort h) {
  return __uint_as_float(((unsigned int)h) << 16);
}
__device__ inline floatx4 mfma16(short8 a, short8 b, floatx4 c) {
  return __builtin_amdgcn_mfma_f32_16x16x32_bf16(a, b, c, 0, 0, 0);
}

// async global->LDS, 16B per lane; dest = wave-uniform base + lane*16
__device__ inline void gload16(const ushort* g, ushort* l) {
  __builtin_amdgcn_global_load_lds(
      (const __attribute__((address_space(1))) void*)g,
      (__attribute__((address_space(3))) void*)l, 16, 0, 0);
}

// stage 16 fp32 -> hi/lo bf16 pairs into LDS (base0 setup GEMM only)
__device__ inline void stage_split16(const float* __restrict__ src, ushort* dsth, ushort* dstl) {
  float fv[16];
  #pragma unroll
  for (int i = 0; i < 4; ++i) *(float4*)&fv[4 * i] = *(const float4*)(src + 4 * i);
  unsigned int ph[8], pl[8];
  #pragma unroll
  for (int i = 0; i < 8; ++i) {
    ushort h0 = f2bf(fv[2 * i]);
    ushort l0 = f2bf(fv[2 * i] - bf2f(h0));
    ushort h1 = f2bf(fv[2 * i + 1]);
    ushort l1 = f2bf(fv[2 * i + 1] - bf2f(h1));
    ph[i] = (unsigned int)h0 | ((unsigned int)h1 << 16);
    pl[i] = (unsigned int)l0 | ((unsigned int)l1 << 16);
  }
  *(uint4*)dsth       = make_uint4(ph[0], ph[1], ph[2], ph[3]);
  *(uint4*)(dsth + 8) = make_uint4(ph[4], ph[5], ph[6], ph[7]);
  *(uint4*)dstl       = make_uint4(pl[0], pl[1], pl[2], pl[3]);
  *(uint4*)(dstl + 8) = make_uint4(pl[4], pl[5], pl[6], pl[7]);
}

// block-reduce then STORE into this block's private bucket (written exactly once).
__device__ inline void cost_store_bucket(float csum, int cnt, float2* __restrict__ cbuf,
                                         int bucket_base) {
  #pragma unroll
  for (int off = 32; off > 0; off >>= 1) {
    csum += __shfl_down(csum, off);
    cnt  += __shfl_down(cnt, off);
  }
  __shared__ float sc[4];
  __shared__ int   si[4];
  int wid = threadIdx.x >> 6;
  if ((threadIdx.x & 63) == 0) { sc[wid] = csum; si[wid] = cnt; }
  __syncthreads();
  if (threadIdx.x == 0) {
    float c = sc[0] + sc[1] + sc[2] + sc[3];
    int   k = si[0] + si[1] + si[2] + si[3];
    float2 v;
    v.x = c * 0.01f;             // per-spike cost = 0.1 * fac/10 * wn = 0.01*fac*wn
    v.y = (float)k;
    cbuf[bucket_base + blockIdx.x] = v;
  }
}

// ---------------- weight row norms ----------------

__global__ __launch_bounds__(64) void wnorm_kernel(const float* __restrict__ w0,
                                                   const float* __restrict__ w1,
                                                   const float* __restrict__ w2,
                                                   float* __restrict__ wn) {
  int r = blockIdx.x;  // 0..3583
  const float* row; int K;
  if (r < 2048)      { row = w0 + (size_t)r * 1024;          K = 1024; }
  else if (r < 3072) { row = w1 + (size_t)(r - 2048) * 2048; K = 2048; }
  else               { row = w2 + (size_t)(r - 3072) * 1024; K = 1024; }
  float ss = 0.f;
  for (int k = threadIdx.x; k < K; k += 64) { float x = row[k]; ss += x * x; }
  #pragma unroll
  for (int off = 32; off > 0; off >>= 1) ss += __shfl_down(ss, off);
  if (threadIdx.x == 0) wn[r] = sqrtf(ss);
}

// ---------------- convert W1,W2 -> bf16 ----------------

__global__ __launch_bounds__(256) void convert_w_kernel(const float* __restrict__ w1,
                                                        const float* __restrict__ w2,
                                                        ushort* __restrict__ w1b,
                                                        ushort* __restrict__ w2b) {
  int i = (blockIdx.x * 256 + threadIdx.x) * 8;   // 1280 blocks -> 2621440 elems
  const float* src; ushort* dst;
  if (i < 2097152) { src = w1 + i; dst = w1b + i; }
  else             { src = w2 + (i - 2097152); dst = w2b + (i - 2097152); }
  float4 a = *(const float4*)src;
  float4 b = *(const float4*)(src + 4);
  unsigned int p0 = (unsigned int)f2bf(a.x) | ((unsigned int)f2bf(a.y) << 16);
  unsigned int p1 = (unsigned int)f2bf(a.z) | ((unsigned int)f2bf(a.w) << 16);
  unsigned int p2 = (unsigned int)f2bf(b.x) | ((unsigned int)f2bf(b.y) << 16);
  unsigned int p3 = (unsigned int)f2bf(b.z) | ((unsigned int)f2bf(b.w) << 16);
  *(uint4*)dst = make_uint4(p0, p1, p2, p3);
}

// ---------------- base0 = inputs @ w0^T via split MFMA (one-time) ----------------

__global__ __launch_bounds__(256) void base0_mfma_kernel(const float* __restrict__ A,  // [256][1024]
                                                         const float* __restrict__ W,  // [2048][1024]
                                                         float* __restrict__ C) {      // [256][2048]
  __shared__ ushort Ah[64][72], Al[64][72], Bh[64][72], Bl[64][72];
  const int tid = threadIdx.x;
  const int m0 = blockIdx.x * 64;
  const int n0 = blockIdx.y * 64;
  const int lane = tid & 63, wv = tid >> 6;
  const int wm = wv & 1, wn2 = wv >> 1;
  const int l15 = lane & 15, quad = lane >> 4;
  const int sr = tid >> 2, scol = (tid & 3) * 16;

  floatx4 acc[2][2];
  #pragma unroll
  for (int i = 0; i < 2; ++i)
    #pragma unroll
    for (int j = 0; j < 2; ++j) acc[i][j] = (floatx4){0.f, 0.f, 0.f, 0.f};

  for (int k0 = 0; k0 < 1024; k0 += 64) {
    stage_split16(A + (size_t)(m0 + sr) * 1024 + k0 + scol, &Ah[sr][scol], &Al[sr][scol]);
    stage_split16(W + (size_t)(n0 + sr) * 1024 + k0 + scol, &Bh[sr][scol], &Bl[sr][scol]);
    __syncthreads();
    #pragma unroll
    for (int ks = 0; ks < 2; ++ks) {
      short8 ah[2], al[2], bh[2], bl[2];
      #pragma unroll
      for (int s = 0; s < 2; ++s) {
        ah[s] = *(const short8*)&Ah[32 * wm + 16 * s + l15][ks * 32 + quad * 8];
        al[s] = *(const short8*)&Al[32 * wm + 16 * s + l15][ks * 32 + quad * 8];
        bh[s] = *(const short8*)&Bh[32 * wn2 + 16 * s + l15][ks * 32 + quad * 8];
        bl[s] = *(const short8*)&Bl[32 * wn2 + 16 * s + l15][ks * 32 + quad * 8];
      }
      #pragma unroll
      for (int sm = 0; sm < 2; ++sm)
        #pragma unroll
        for (int sn = 0; sn < 2; ++sn) {
          acc[sm][sn] = mfma16(ah[sm], bh[sn], acc[sm][sn]);
          acc[sm][sn] = mfma16(ah[sm], bl[sn], acc[sm][sn]);
          acc[sm][sn] = mfma16(al[sm], bh[sn], acc[sm][sn]);
        }
    }
    __syncthreads();
  }
  #pragma unroll
  for (int sm = 0; sm < 2; ++sm)
    #pragma unroll
    for (int sn = 0; sn < 2; ++sn)
      #pragma unroll
      for (int r = 0; r < 4; ++r) {
        int m = m0 + 32 * wm + 16 * sm + quad * 4 + r;
        int n = n0 + 32 * wn2 + 16 * sn + l15;
        C[(size_t)m * 2048 + n] = acc[sm][sn][r];
      }
}

// ------- LDS-staged batched GEMM with K-split: P[sl][4096][N] = A[:, sl] @ W[:, sl]^T ------
// 128x128 tile, BK=64, 4 waves, double-buffered LDS (64KB), global_load_lds staging with
// source-side swizzle, XCD-bijective block swizzle, K-split NSPLIT.

template<int K, int N, int NSPLIT>
__global__ __launch_bounds__(256) void gemm_lds_kernel(const ushort* __restrict__ A,
                                                       const ushort* __restrict__ W,
                                                       float* __restrict__ P) {
  __shared__ __attribute__((aligned(16))) ushort As[2][128 * 64];
  __shared__ __attribute__((aligned(16))) ushort Bs[2][128 * 64];
  constexpr int KS = K / NSPLIT;       // K per slice
  constexpr int NSTEP = KS / 64;
  constexpr int NT = N / 128;
  constexpr int MT = 32;               // 4096/128
  constexpr int NWG = MT * NT * NSPLIT;  // divisible by 8

  // XCD-bijective swizzle: XCD x processes contiguous orig chunk [x*NWG/8, ...)
  const int orig = ((int)blockIdx.x % 8) * (NWG / 8) + (int)blockIdx.x / 8;
  const int sl = orig / (MT * NT);
  const int rem = orig % (MT * NT);
  const int m0 = (rem / NT) * 128;
  const int n0 = (rem % NT) * 128;

  const int tid = threadIdx.x;
  const int lane = tid & 63, wv = tid >> 6;
  const int wm = wv & 1, wn2 = wv >> 1;
  const int l15 = lane & 15, quad = lane >> 4;

  const ushort* Ab = A + (size_t)m0 * K + sl * KS;
  const ushort* Wb = W + (size_t)n0 * K + sl * KS;

  // staging: one gload16 covers 8 rows (64 lanes x 16B = 1KB, rows of 128B).
  // lane l -> row r0+(l>>3), LDS slot l&7; global slot pre-swizzled so
  // LDS[r][s] = G[r][s^(r&7)] with LINEAR LDS dest. 16 gload16 per matrix per step.
  const int lrow = lane >> 3;                       // 0..7
  const int lslot = (lane & 7) ^ lrow;              // inverse-swizzled source slot

  floatx4 acc[4][4];
  #pragma unroll
  for (int i = 0; i < 4; ++i)
    #pragma unroll
    for (int j = 0; j < 4; ++j) acc[i][j] = (floatx4){0.f, 0.f, 0.f, 0.f};

  auto stage = [&](int buf, int k0) {
    #pragma unroll
    for (int h = 0; h < 4; ++h) {
      int r0 = wv * 32 + h * 8;                      // 4 waves x 4 calls x 8 rows = 128
      const ushort* ga = Ab + (size_t)(r0 + lrow) * K + k0 + lslot * 8;
      const ushort* gb = Wb + (size_t)(r0 + lrow) * K + k0 + lslot * 8;
      gload16(ga, &As[buf][r0 * 64]);
      gload16(gb, &Bs[buf][r0 * 64]);
    }
  };
  auto compute = [&](int buf) {
    #pragma unroll
    for (int ks = 0; ks < 2; ++ks) {
      short8 af[4], bf[4];
      #pragma unroll
      for (int s = 0; s < 4; ++s) {
        int arow = wm * 64 + s * 16 + l15;
        int brow = wn2 * 64 + s * 16 + l15;
        af[s] = *(const short8*)&As[buf][arow * 64 + (((ks * 4 + quad) ^ (arow & 7)) << 3)];
        bf[s] = *(const short8*)&Bs[buf][brow * 64 + (((ks * 4 + quad) ^ (brow & 7)) << 3)];
      }
      #pragma unroll
      for (int sm = 0; sm < 4; ++sm)
        #pragma unroll
        for (int sn = 0; sn < 4; ++sn)
          acc[sm][sn] = mfma16(af[sm], bf[sn], acc[sm][sn]);
    }
  };

  stage(0, 0);
  __syncthreads();                      // drains vmcnt -> buf0 ready
  for (int kk = 0; kk < NSTEP; ++kk) {
    int buf = kk & 1;
    if (kk + 1 < NSTEP) stage(buf ^ 1, (kk + 1) * 64);  // issue early, lands during compute
    compute(buf);
    __syncthreads();                    // drain + barrier: next buf ready, this buf reusable
  }

  float* Ps = P + (size_t)sl * 4096 * N;
  #pragma unroll
  for (int sm = 0; sm < 4; ++sm)
    #pragma unroll
    for (int sn = 0; sn < 4; ++sn)
      #pragma unroll
      for (int r = 0; r < 4; ++r) {
        int m = m0 + wm * 64 + sm * 16 + quad * 4 + r;
        int n = n0 + wn2 * 64 + sn * 16 + l15;
        Ps[(size_t)m * N + n] = acc[sm][sn][r];
      }
}

// ---------------- L0 LIF: all 16 steps, state in registers ----------------
// 512 blocks x 256 threads x 4 elems = 524288 elems of (b, n0)

__global__ __launch_bounds__(256) void l0_lif_kernel(const float* __restrict__ base0,
                                                     const float* __restrict__ cn0,
                                                     const float* __restrict__ tn0,
                                                     const float* __restrict__ th0,
                                                     const float* __restrict__ wn0,
                                                     ushort* __restrict__ sp0,
                                                     float2* __restrict__ cbuf) {
  const int e = (blockIdx.x * 256 + threadIdx.x) * 4;
  const int n = e & 2047;
  float4 bb  = *(const float4*)(base0 + e);
  float4 th4 = *(const float4*)(th0 + n);
  float4 wn4 = *(const float4*)(wn0 + n);
  float bbv[4] = {bb.x, bb.y, bb.z, bb.w};
  float thv[4] = {th4.x, th4.y, th4.z, th4.w};
  float wnq[4] = {wn4.x, wn4.y, wn4.z, wn4.w};
  float V[4] = {0.f, 0.f, 0.f, 0.f};
  bool prev[4] = {false, false, false, false};
  float csum = 0.f; int cnt = 0;
  #pragma unroll 2
  for (int t = 1; t <= T_STEPS; ++t) {
    size_t off = (size_t)(t - 1) * 524288 + e;
    float4 c4 = *(const float4*)(cn0 + off);
    float4 t4 = *(const float4*)(tn0 + off);
    float cnv[4] = {c4.x, c4.y, c4.z, c4.w};
    float tnv[4] = {t4.x, t4.y, t4.z, t4.w};
    float f = (t <= 7) ? 10.f : (float)(17 - t);
    ushort sout[4];
    #pragma unroll
    for (int j = 0; j < 4; ++j) {
      float cur = bbv[j] + cnv[j] * (0.05f * wnq[j]);
      float Vn = prev[j] ? V[j] : (0.95f * V[j] + cur);
      float thr = thv[j] + tnv[j] * 0.1f;
      bool sp = (!prev[j]) && (Vn > thr);
      V[j] = sp ? 0.f : Vn;
      sout[j] = sp ? (ushort)0x3F80 : (ushort)0;
      prev[j] = sp;
      if (sp) { csum += wnq[j] * f; cnt++; }
    }
    ushort4 sq; sq.x = sout[0]; sq.y = sout[1]; sq.z = sout[2]; sq.w = sout[3];
    *(ushort4*)(sp0 + off) = sq;
  }
  cost_store_bucket(csum, cnt, cbuf, 0);
}

// -------- L1/L2 LIF: all 16 steps from 2 partial slices, state in registers --------

template<int N, bool LAST>
__global__ __launch_bounds__(256) void lif_seq_kernel(const float* __restrict__ P,  // [2][4096][N]
                                                      const float* __restrict__ cn,
                                                      const float* __restrict__ tn,
                                                      const float* __restrict__ th,
                                                      const float* __restrict__ wnv,
                                                      ushort* __restrict__ spout,
                                                      float* __restrict__ outF,
                                                      float2* __restrict__ cbuf,
                                                      int bucket_base) {
  constexpr int SZ = 256 * N;
  constexpr size_t SLICE = (size_t)16 * SZ;   // 4096*N
  const int e = (blockIdx.x * 256 + threadIdx.x) * 4;
  const int n = e & (N - 1);
  float4 th4 = *(const float4*)(th + n);
  float4 wn4 = *(const float4*)(wnv + n);
  float thv[4] = {th4.x, th4.y, th4.z, th4.w};
  float wnq[4] = {wn4.x, wn4.y, wn4.z, wn4.w};
  float V[4] = {0.f, 0.f, 0.f, 0.f};
  bool prev[4] = {false, false, false, false};
  float csum = 0.f; int cnt = 0;
  #pragma unroll 2
  for (int t = 1; t <= T_STEPS; ++t) {
    size_t off = (size_t)(t - 1) * SZ + e;
    float4 p0 = *(const float4*)(P + off);
    float4 p1 = *(const float4*)(P + SLICE + off);
    float4 c4 = *(const float4*)(cn + off);
    float4 t4 = *(const float4*)(tn + off);
    float av[4]  = {p0.x + p1.x, p0.y + p1.y, p0.z + p1.z, p0.w + p1.w};
    float cnv[4] = {c4.x, c4.y, c4.z, c4.w};
    float tnv[4] = {t4.x, t4.y, t4.z, t4.w};
    float f = (t <= 7) ? 10.f : (float)(17 - t);
    ushort sout[4];
    #pragma unroll
    for (int j = 0; j < 4; ++j) {
      float cur = av[j] + cnv[j] * (0.05f * wnq[j]);
      float Vn = prev[j] ? V[j] : (0.95f * V[j] + cur);
      float thr = thv[j] + tnv[j] * 0.1f;
      bool sp = (!prev[j]) && (Vn > thr);
      V[j] = sp ? 0.f : Vn;
      sout[j] = sp ? (ushort)0x3F80 : (ushort)0;
      prev[j] = sp;
      if (sp) { csum += wnq[j] * f; cnt++; }
    }
    if (!LAST) {
      ushort4 sq; sq.x = sout[0]; sq.y = sout[1]; sq.z = sout[2]; sq.w = sout[3];
      *(ushort4*)(spout + off) = sq;
    } else if (t == T_STEPS) {
      *(float4*)(outF + e) = make_float4(sout[0] ? 1.f : 0.f, sout[1] ? 1.f : 0.f,
                                         sout[2] ? 1.f : 0.f, sout[3] ? 1.f : 0.f);
    }
  }
  cost_store_bucket(csum, cnt, cbuf, bucket_base);
}

// ---------------- finalize: reduce 896 buckets -> cost, entropy ----------------

__global__ __launch_bounds__(256) void finalize_kernel(const float2* __restrict__ cbuf,
                                                       float* __restrict__ out) {
  float c = 0.f, k = 0.f;
  for (int i = threadIdx.x; i < 896; i += 256) {
    float2 v = cbuf[i];
    c += v.x; k += v.y;
  }
  #pragma unroll
  for (int off = 32; off > 0; off >>= 1) {
    c += __shfl_down(c, off);
    k += __shfl_down(k, off);
  }
  __shared__ float sc[4], sk[4];
  int wid = threadIdx.x >> 6;
  if ((threadIdx.x & 63) == 0) { sc[wid] = c; sk[wid] = k; }
  __syncthreads();
  if (threadIdx.x == 0) {
    float cost = sc[0] + sc[1] + sc[2] + sc[3];
    float tot  = sk[0] + sk[1] + sk[2] + sk[3];
    float p1 = tot / 14680064.f;   // T*B*(2048+1024+512)
    float p0 = 1.f - p1;
    float ent = -(p1 * log2f(p1 + 1e-12f) + p0 * log2f(p0 + 1e-12f));
    out[131072] = cost;
    out[131073] = ent;
  }
}

// ---------------- launch ----------------

extern "C" void kernel_launch(void* const* d_in, const int* in_sizes, int n_in,
                              void* d_out, int out_size, void* d_ws, size_t ws_size,
                              hipStream_t stream) {
  const float* inputs = (const float*)d_in[0];
  const float* w0  = (const float*)d_in[1];
  const float* th0 = (const float*)d_in[2];
  const float* cn0 = (const float*)d_in[3];
  const float* tn0 = (const float*)d_in[4];
  const float* w1  = (const float*)d_in[5];
  const float* th1 = (const float*)d_in[6];
  const float* cn1 = (const float*)d_in[7];
  const float* tn1 = (const float*)d_in[8];
  const float* w2  = (const float*)d_in[9];
  const float* th2 = (const float*)d_in[10];
  const float* cn2 = (const float*)d_in[11];
  const float* tn2 = (const float*)d_in[12];
  float* out = (float*)d_out;
  float* ws  = (float*)d_ws;

  // workspace layout (float slots), ~67 MB total
  float* wn    = ws;                        // 4096 (3584 used)
  float* base0 = ws + 4096;                 // 524288 fp32 [256][2048]
  float* P1    = base0 + 524288;            // 8388608 fp32 [2][4096][1024] (32 MB)
  ushort* w1b  = (ushort*)(P1 + 8388608);   // 2097152 ushort [1024][2048]
  ushort* w2b  = w1b + 2097152;             // 524288 ushort [512][1024]
  ushort* sp0  = w2b + 524288;              // 8388608 ushort [16][256][2048] (16 MB)
  ushort* sp1  = sp0 + 8388608;             // 4194304 ushort [16][256][1024]
  float2* cbuf = (float2*)(sp1 + 4194304);  // 896 float2
  float* P2    = (float*)sp0;               // ALIAS: [2][4096][512] (16 MB); sp0 dead
                                            // before GEMM2 writes P2 (GEMM1 done).

  wnorm_kernel<<<3584, 64, 0, stream>>>(w0, w1, w2, wn);
  convert_w_kernel<<<1280, 256, 0, stream>>>(w1, w2, w1b, w2b);
  base0_mfma_kernel<<<dim3(4, 32), 256, 0, stream>>>(inputs, w0, base0);

  // L0: all 16 steps -> sp0, buckets [0,512)
  l0_lif_kernel<<<512, 256, 0, stream>>>(base0, cn0, tn0, th0, wn, sp0, cbuf);

  // GEMM1: P1[2][4096][1024], K-split 2 (512 blocks, 2/CU)
  gemm_lds_kernel<2048, 1024, 2><<<512, 256, 0, stream>>>(sp0, w1b, P1);

  // L1: all 16 steps, sums 2 slices -> sp1, buckets [512,768)
  lif_seq_kernel<1024, false><<<256, 256, 0, stream>>>(P1, cn1, tn1, th1, wn + 2048,
                                                       sp1, nullptr, cbuf, 512);

  // GEMM2: P2[2][4096][512], K-split 2 (256 blocks)
  gemm_lds_kernel<1024, 512, 2><<<256, 256, 0, stream>>>(sp1, w2b, P2);

  // L2: all 16 steps, sums 2 slices -> out (t=16), buckets [768,896)
  lif_seq_kernel<512, true><<<128, 256, 0, stream>>>(P2, cn2, tn2, th2, wn + 3072,
                                                     nullptr, out, cbuf, 768);

  finalize_kernel<<<1, 256, 0, stream>>>(cbuf, out);
}

// Round 7
// 290.950 us; speedup vs baseline: 1.6260x; 1.0133x over previous
//
#include <hip/hip_runtime.h>
#include <math.h>

// NeuromorphicPrivacyNetwork: 3-layer LIF SNN, T=16, B=256, sizes 1024->2048->1024->512.
// Round-13b: RESUBMISSION of round-13 (container infra failure, kernel never ran).
// Design: fuse LIF into GEMM epilogues. Spike matrices re-laid-out as row m = b*16+t
// (batch-major, time-minor), so a 128-row GEMM tile = 8 batches x all 16 steps, and the
// LIF recurrence runs in-register in the epilogue: thread owns t=quad*4+r of each chain;
// recurrence serializes over quads via 4x {masked 4-step compute + __shfl broadcast of
// (V,prev) from quad qq} (lanes with equal l15 share one (b,n) chain).
// Eliminates P1/P2 fp32 partials (96MB traffic) + lif1/lif2 dispatches.
// GEMM tile 128x64, BK=64, full K, 4 waves (64x32 each), dbuf LDS 48KB (3 blocks/CU),
// gload_lds w/ source-side swizzle, XCD-bijective block swizzle (from round-12, passed).
// 7 dispatches: wnorm, convert, base0, l0, gemm1+lif1, gemm2+lif2(+out), finalize.
// Buckets: l0 [0,512), gemm1 [512,1024), gemm2 [1024,1280). All 1280 written exactly once.

#define T_STEPS 16

typedef short short8 __attribute__((ext_vector_type(8)));
typedef float floatx4 __attribute__((ext_vector_type(4)));

__device__ inline ushort f2bf(float x) {
  unsigned int u = __float_as_uint(x);
  unsigned int r = (u + 0x7FFFu + ((u >> 16) & 1u)) >> 16;
  return (ushort)r;
}
__device__ inline float bf2f(ushort h) {
  return __uint_as_float(((unsigned int)h) << 16);
}
__device__ inline floatx4 mfma16(short8 a, short8 b, floatx4 c) {
  return __builtin_amdgcn_mfma_f32_16x16x32_bf16(a, b, c, 0, 0, 0);
}

// async global->LDS, 16B per lane; dest = wave-uniform base + lane*16
__device__ inline void gload16(const ushort* g, ushort* l) {
  __builtin_amdgcn_global_load_lds(
      (const __attribute__((address_space(1))) void*)g,
      (__attribute__((address_space(3))) void*)l, 16, 0, 0);
}

// stage 16 fp32 -> hi/lo bf16 pairs into LDS (base0 setup GEMM only)
__device__ inline void stage_split16(const float* __restrict__ src, ushort* dsth, ushort* dstl) {
  float fv[16];
  #pragma unroll
  for (int i = 0; i < 4; ++i) *(float4*)&fv[4 * i] = *(const float4*)(src + 4 * i);
  unsigned int ph[8], pl[8];
  #pragma unroll
  for (int i = 0; i < 8; ++i) {
    ushort h0 = f2bf(fv[2 * i]);
    ushort l0 = f2bf(fv[2 * i] - bf2f(h0));
    ushort h1 = f2bf(fv[2 * i + 1]);
    ushort l1 = f2bf(fv[2 * i + 1] - bf2f(h1));
    ph[i] = (unsigned int)h0 | ((unsigned int)h1 << 16);
    pl[i] = (unsigned int)l0 | ((unsigned int)l1 << 16);
  }
  *(uint4*)dsth       = make_uint4(ph[0], ph[1], ph[2], ph[3]);
  *(uint4*)(dsth + 8) = make_uint4(ph[4], ph[5], ph[6], ph[7]);
  *(uint4*)dstl       = make_uint4(pl[0], pl[1], pl[2], pl[3]);
  *(uint4*)(dstl + 8) = make_uint4(pl[4], pl[5], pl[6], pl[7]);
}

// block-reduce then STORE into this block's private bucket (written exactly once).
__device__ inline void cost_store_bucket(float csum, int cnt, float2* __restrict__ cbuf,
                                         int bucket_base) {
  #pragma unroll
  for (int off = 32; off > 0; off >>= 1) {
    csum += __shfl_down(csum, off);
    cnt  += __shfl_down(cnt, off);
  }
  __shared__ float sc[4];
  __shared__ int   si[4];
  int wid = threadIdx.x >> 6;
  if ((threadIdx.x & 63) == 0) { sc[wid] = csum; si[wid] = cnt; }
  __syncthreads();
  if (threadIdx.x == 0) {
    float c = sc[0] + sc[1] + sc[2] + sc[3];
    int   k = si[0] + si[1] + si[2] + si[3];
    float2 v;
    v.x = c * 0.01f;             // per-spike cost = 0.1 * fac/10 * wn = 0.01*fac*wn
    v.y = (float)k;
    cbuf[bucket_base + blockIdx.x] = v;
  }
}

// ---------------- weight row norms ----------------

__global__ __launch_bounds__(64) void wnorm_kernel(const float* __restrict__ w0,
                                                   const float* __restrict__ w1,
                                                   const float* __restrict__ w2,
                                                   float* __restrict__ wn) {
  int r = blockIdx.x;  // 0..3583
  const float* row; int K;
  if (r < 2048)      { row = w0 + (size_t)r * 1024;          K = 1024; }
  else if (r < 3072) { row = w1 + (size_t)(r - 2048) * 2048; K = 2048; }
  else               { row = w2 + (size_t)(r - 3072) * 1024; K = 1024; }
  float ss = 0.f;
  for (int k = threadIdx.x; k < K; k += 64) { float x = row[k]; ss += x * x; }
  #pragma unroll
  for (int off = 32; off > 0; off >>= 1) ss += __shfl_down(ss, off);
  if (threadIdx.x == 0) wn[r] = sqrtf(ss);
}

// ---------------- convert W1,W2 -> bf16 ----------------

__global__ __launch_bounds__(256) void convert_w_kernel(const float* __restrict__ w1,
                                                        const float* __restrict__ w2,
                                                        ushort* __restrict__ w1b,
                                                        ushort* __restrict__ w2b) {
  int i = (blockIdx.x * 256 + threadIdx.x) * 8;   // 1280 blocks -> 2621440 elems
  const float* src; ushort* dst;
  if (i < 2097152) { src = w1 + i; dst = w1b + i; }
  else             { src = w2 + (i - 2097152); dst = w2b + (i - 2097152); }
  float4 a = *(const float4*)src;
  float4 b = *(const float4*)(src + 4);
  unsigned int p0 = (unsigned int)f2bf(a.x) | ((unsigned int)f2bf(a.y) << 16);
  unsigned int p1 = (unsigned int)f2bf(a.z) | ((unsigned int)f2bf(a.w) << 16);
  unsigned int p2 = (unsigned int)f2bf(b.x) | ((unsigned int)f2bf(b.y) << 16);
  unsigned int p3 = (unsigned int)f2bf(b.z) | ((unsigned int)f2bf(b.w) << 16);
  *(uint4*)dst = make_uint4(p0, p1, p2, p3);
}

// ---------------- base0 = inputs @ w0^T via split MFMA (one-time) ----------------

__global__ __launch_bounds__(256) void base0_mfma_kernel(const float* __restrict__ A,  // [256][1024]
                                                         const float* __restrict__ W,  // [2048][1024]
                                                         float* __restrict__ C) {      // [256][2048]
  __shared__ ushort Ah[64][72], Al[64][72], Bh[64][72], Bl[64][72];
  const int tid = threadIdx.x;
  const int m0 = blockIdx.x * 64;
  const int n0 = blockIdx.y * 64;
  const int lane = tid & 63, wv = tid >> 6;
  const int wm = wv & 1, wn2 = wv >> 1;
  const int l15 = lane & 15, quad = lane >> 4;
  const int sr = tid >> 2, scol = (tid & 3) * 16;

  floatx4 acc[2][2];
  #pragma unroll
  for (int i = 0; i < 2; ++i)
    #pragma unroll
    for (int j = 0; j < 2; ++j) acc[i][j] = (floatx4){0.f, 0.f, 0.f, 0.f};

  for (int k0 = 0; k0 < 1024; k0 += 64) {
    stage_split16(A + (size_t)(m0 + sr) * 1024 + k0 + scol, &Ah[sr][scol], &Al[sr][scol]);
    stage_split16(W + (size_t)(n0 + sr) * 1024 + k0 + scol, &Bh[sr][scol], &Bl[sr][scol]);
    __syncthreads();
    #pragma unroll
    for (int ks = 0; ks < 2; ++ks) {
      short8 ah[2], al[2], bh[2], bl[2];
      #pragma unroll
      for (int s = 0; s < 2; ++s) {
        ah[s] = *(const short8*)&Ah[32 * wm + 16 * s + l15][ks * 32 + quad * 8];
        al[s] = *(const short8*)&Al[32 * wm + 16 * s + l15][ks * 32 + quad * 8];
        bh[s] = *(const short8*)&Bh[32 * wn2 + 16 * s + l15][ks * 32 + quad * 8];
        bl[s] = *(const short8*)&Bl[32 * wn2 + 16 * s + l15][ks * 32 + quad * 8];
      }
      #pragma unroll
      for (int sm = 0; sm < 2; ++sm)
        #pragma unroll
        for (int sn = 0; sn < 2; ++sn) {
          acc[sm][sn] = mfma16(ah[sm], bh[sn], acc[sm][sn]);
          acc[sm][sn] = mfma16(ah[sm], bl[sn], acc[sm][sn]);
          acc[sm][sn] = mfma16(al[sm], bh[sn], acc[sm][sn]);
        }
    }
    __syncthreads();
  }
  #pragma unroll
  for (int sm = 0; sm < 2; ++sm)
    #pragma unroll
    for (int sn = 0; sn < 2; ++sn)
      #pragma unroll
      for (int r = 0; r < 4; ++r) {
        int m = m0 + 32 * wm + 16 * sm + quad * 4 + r;
        int n = n0 + 32 * wn2 + 16 * sn + l15;
        C[(size_t)m * 2048 + n] = acc[sm][sn][r];
      }
}

// ---- fused GEMM + LIF: A[4096][K] (rows m=b*16+t) @ W[N][K]^T, LIF in epilogue ----
// Tile 128x64, BK=64, 4 waves (each 64x32), full K, dbuf LDS 48KB.

template<int K, int N, bool LAST>
__global__ __launch_bounds__(256) void gemm_lif_kernel(const ushort* __restrict__ A,
                                                       const ushort* __restrict__ W,
                                                       const float* __restrict__ cn,
                                                       const float* __restrict__ tn,
                                                       const float* __restrict__ th,
                                                       const float* __restrict__ wnv,
                                                       ushort* __restrict__ spout,  // [4096][N] (b*16+t rows), null if LAST
                                                       float* __restrict__ outF,    // [256][N] if LAST
                                                       float2* __restrict__ cbuf,
                                                       int bucket_base) {
  __shared__ __attribute__((aligned(16))) ushort As[2][128 * 64];
  __shared__ __attribute__((aligned(16))) ushort Bs[2][64 * 64];
  constexpr int NSTEP = K / 64;
  constexpr int NT = N / 64;           // n-tiles
  constexpr int MT = 32;               // 4096/128
  constexpr int NWG = MT * NT;         // 512 (GEMM1) / 256 (GEMM2), divisible by 8

  // XCD-bijective swizzle
  const int orig = ((int)blockIdx.x % 8) * (NWG / 8) + (int)blockIdx.x / 8;
  const int m0 = (orig / NT) * 128;
  const int n0 = (orig % NT) * 64;

  const int tid = threadIdx.x;
  const int lane = tid & 63, wv = tid >> 6;
  const int wm = wv & 1, wn2 = wv >> 1;
  const int l15 = lane & 15, quad = lane >> 4;

  const ushort* Ab = A + (size_t)m0 * K;
  const ushort* Wb = W + (size_t)n0 * K;

  const int lrow = lane >> 3;                       // 0..7
  const int lslot = (lane & 7) ^ lrow;              // inverse-swizzled source slot

  floatx4 acc[4][2];
  #pragma unroll
  for (int i = 0; i < 4; ++i)
    #pragma unroll
    for (int j = 0; j < 2; ++j) acc[i][j] = (floatx4){0.f, 0.f, 0.f, 0.f};

  auto stage = [&](int buf, int k0) {
    #pragma unroll
    for (int h = 0; h < 4; ++h) {                    // A: 128 rows = 4 waves x 4 x 8
      int r0 = wv * 32 + h * 8;
      gload16(Ab + (size_t)(r0 + lrow) * K + k0 + lslot * 8, &As[buf][r0 * 64]);
    }
    #pragma unroll
    for (int h = 0; h < 2; ++h) {                    // B: 64 rows = 4 waves x 2 x 8
      int r0 = wv * 16 + h * 8;
      gload16(Wb + (size_t)(r0 + lrow) * K + k0 + lslot * 8, &Bs[buf][r0 * 64]);
    }
  };
  auto compute = [&](int buf) {
    #pragma unroll
    for (int ks = 0; ks < 2; ++ks) {
      short8 af[4], bf[2];
      #pragma unroll
      for (int s = 0; s < 4; ++s) {
        int arow = wm * 64 + s * 16 + l15;
        af[s] = *(const short8*)&As[buf][arow * 64 + (((ks * 4 + quad) ^ (arow & 7)) << 3)];
      }
      #pragma unroll
      for (int s = 0; s < 2; ++s) {
        int brow = wn2 * 32 + s * 16 + l15;
        bf[s] = *(const short8*)&Bs[buf][brow * 64 + (((ks * 4 + quad) ^ (brow & 7)) << 3)];
      }
      #pragma unroll
      for (int sm = 0; sm < 4; ++sm)
        #pragma unroll
        for (int sn = 0; sn < 2; ++sn)
          acc[sm][sn] = mfma16(af[sm], bf[sn], acc[sm][sn]);
    }
  };

  stage(0, 0);
  __syncthreads();
  for (int kk = 0; kk < NSTEP; ++kk) {
    int buf = kk & 1;
    if (kk + 1 < NSTEP) stage(buf ^ 1, (kk + 1) * 64);
    compute(buf);
    __syncthreads();
  }

  // ---- epilogue: in-register LIF over t, serialized across quads ----
  // Thread owns C[m][n] for m = m0 + wm*64 + sm*16 + quad*4 + r, n = n0 + wn2*32 + sn*16 + l15.
  // Row m = b*16 + (t-1): b = m>>4 (sm-group constant), t-1 = quad*4+r (thread-local).
  float csum = 0.f; int cnt = 0;
  #pragma unroll
  for (int sm = 0; sm < 4; ++sm) {
    const int b = (m0 >> 4) + wm * 4 + sm;
    #pragma unroll
    for (int sn = 0; sn < 2; ++sn) {
      const int n = n0 + wn2 * 32 + sn * 16 + l15;
      float cnv[4], tnv[4];
      #pragma unroll
      for (int r = 0; r < 4; ++r) {
        size_t off = (size_t)(quad * 4 + r) * (256 * N) + (size_t)b * N + n;
        cnv[r] = cn[off];
        tnv[r] = tn[off];
      }
      const float thn = th[n];
      const float wnn = wnv[n];
      float V = 0.f; int prev = 0;
      ushort skeep[4] = {0, 0, 0, 0};
      #pragma unroll
      for (int qq = 0; qq < 4; ++qq) {
        float Vl = V; int pl = prev;
        ushort slocal[4];
        #pragma unroll
        for (int r = 0; r < 4; ++r) {
          float cur = acc[sm][sn][r] + cnv[r] * (0.05f * wnn);
          float Vn = pl ? Vl : (0.95f * Vl + cur);
          float thr = thn + tnv[r] * 0.1f;
          bool sp = (!pl) && (Vn > thr);
          Vl = sp ? 0.f : Vn;
          slocal[r] = sp ? (ushort)0x3F80 : (ushort)0;
          pl = sp ? 1 : 0;
        }
        if (quad == qq) {
          #pragma unroll
          for (int r = 0; r < 4; ++r) skeep[r] = slocal[r];
        }
        V = __shfl(Vl, l15 + (qq << 4));
        prev = __shfl(pl, l15 + (qq << 4));
      }
      #pragma unroll
      for (int r = 0; r < 4; ++r) {
        int t = quad * 4 + r + 1;
        float f = (t <= 7) ? 10.f : (float)(17 - t);
        if (skeep[r]) { csum += wnn * f; cnt++; }
      }
      if (!LAST) {
        const int mbase = m0 + wm * 64 + sm * 16 + quad * 4;
        #pragma unroll
        for (int r = 0; r < 4; ++r)
          spout[(size_t)(mbase + r) * N + n] = skeep[r];
      } else {
        if (quad == 3) outF[(size_t)b * N + n] = skeep[3] ? 1.f : 0.f;  // t=16
      }
    }
  }
  cost_store_bucket(csum, cnt, cbuf, bucket_base);
}

// ---------------- L0 LIF: all 16 steps, state in registers ----------------
// 512 blocks x 256 threads x 4 elems; sp0 written in m = b*16 + (t-1) row layout.

__global__ __launch_bounds__(256) void l0_lif_kernel(const float* __restrict__ base0,
                                                     const float* __restrict__ cn0,
                                                     const float* __restrict__ tn0,
                                                     const float* __restrict__ th0,
                                                     const float* __restrict__ wn0,
                                                     ushort* __restrict__ sp0,
                                                     float2* __restrict__ cbuf) {
  const int e = (blockIdx.x * 256 + threadIdx.x) * 4;
  const int n = e & 2047;
  const int b = e >> 11;
  float4 bb  = *(const float4*)(base0 + e);
  float4 th4 = *(const float4*)(th0 + n);
  float4 wn4 = *(const float4*)(wn0 + n);
  float bbv[4] = {bb.x, bb.y, bb.z, bb.w};
  float thv[4] = {th4.x, th4.y, th4.z, th4.w};
  float wnq[4] = {wn4.x, wn4.y, wn4.z, wn4.w};
  float V[4] = {0.f, 0.f, 0.f, 0.f};
  bool prev[4] = {false, false, false, false};
  float csum = 0.f; int cnt = 0;
  #pragma unroll 2
  for (int t = 1; t <= T_STEPS; ++t) {
    size_t off = (size_t)(t - 1) * 524288 + e;
    float4 c4 = *(const float4*)(cn0 + off);
    float4 t4 = *(const float4*)(tn0 + off);
    float cnv[4] = {c4.x, c4.y, c4.z, c4.w};
    float tnv[4] = {t4.x, t4.y, t4.z, t4.w};
    float f = (t <= 7) ? 10.f : (float)(17 - t);
    ushort sout[4];
    #pragma unroll
    for (int j = 0; j < 4; ++j) {
      float cur = bbv[j] + cnv[j] * (0.05f * wnq[j]);
      float Vn = prev[j] ? V[j] : (0.95f * V[j] + cur);
      float thr = thv[j] + tnv[j] * 0.1f;
      bool sp = (!prev[j]) && (Vn > thr);
      V[j] = sp ? 0.f : Vn;
      sout[j] = sp ? (ushort)0x3F80 : (ushort)0;
      prev[j] = sp;
      if (sp) { csum += wnq[j] * f; cnt++; }
    }
    ushort4 sq; sq.x = sout[0]; sq.y = sout[1]; sq.z = sout[2]; sq.w = sout[3];
    *(ushort4*)(sp0 + (size_t)(b * 16 + t - 1) * 2048 + n) = sq;
  }
  cost_store_bucket(csum, cnt, cbuf, 0);
}

// ---------------- finalize: reduce 1280 buckets -> cost, entropy ----------------

__global__ __launch_bounds__(256) void finalize_kernel(const float2* __restrict__ cbuf,
                                                       float* __restrict__ out) {
  float c = 0.f, k = 0.f;
  for (int i = threadIdx.x; i < 1280; i += 256) {
    float2 v = cbuf[i];
    c += v.x; k += v.y;
  }
  #pragma unroll
  for (int off = 32; off > 0; off >>= 1) {
    c += __shfl_down(c, off);
    k += __shfl_down(k, off);
  }
  __shared__ float sc[4], sk[4];
  int wid = threadIdx.x >> 6;
  if ((threadIdx.x & 63) == 0) { sc[wid] = c; sk[wid] = k; }
  __syncthreads();
  if (threadIdx.x == 0) {
    float cost = sc[0] + sc[1] + sc[2] + sc[3];
    float tot  = sk[0] + sk[1] + sk[2] + sk[3];
    float p1 = tot / 14680064.f;   // T*B*(2048+1024+512)
    float p0 = 1.f - p1;
    float ent = -(p1 * log2f(p1 + 1e-12f) + p0 * log2f(p0 + 1e-12f));
    out[131072] = cost;
    out[131073] = ent;
  }
}

// ---------------- launch ----------------

extern "C" void kernel_launch(void* const* d_in, const int* in_sizes, int n_in,
                              void* d_out, int out_size, void* d_ws, size_t ws_size,
                              hipStream_t stream) {
  const float* inputs = (const float*)d_in[0];
  const float* w0  = (const float*)d_in[1];
  const float* th0 = (const float*)d_in[2];
  const float* cn0 = (const float*)d_in[3];
  const float* tn0 = (const float*)d_in[4];
  const float* w1  = (const float*)d_in[5];
  const float* th1 = (const float*)d_in[6];
  const float* cn1 = (const float*)d_in[7];
  const float* tn1 = (const float*)d_in[8];
  const float* w2  = (const float*)d_in[9];
  const float* th2 = (const float*)d_in[10];
  const float* cn2 = (const float*)d_in[11];
  const float* tn2 = (const float*)d_in[12];
  float* out = (float*)d_out;
  float* ws  = (float*)d_ws;

  // workspace layout (float slots), ~35 MB total
  float* wn    = ws;                        // 4096 (3584 used)
  float* base0 = ws + 4096;                 // 524288 fp32 [256][2048]
  ushort* w1b  = (ushort*)(base0 + 524288); // 2097152 ushort [1024][2048]
  ushort* w2b  = w1b + 2097152;             // 524288 ushort [512][1024]
  ushort* sp0  = w2b + 524288;              // 8388608 ushort [4096][2048] (m=b*16+t)
  ushort* sp1  = sp0 + 8388608;             // 4194304 ushort [4096][1024] (m=b*16+t)
  float2* cbuf = (float2*)(sp1 + 4194304);  // 1280 float2

  wnorm_kernel<<<3584, 64, 0, stream>>>(w0, w1, w2, wn);
  convert_w_kernel<<<1280, 256, 0, stream>>>(w1, w2, w1b, w2b);
  base0_mfma_kernel<<<dim3(4, 32), 256, 0, stream>>>(inputs, w0, base0);

  // L0: all 16 steps -> sp0 (b*16+t layout), buckets [0,512)
  l0_lif_kernel<<<512, 256, 0, stream>>>(base0, cn0, tn0, th0, wn, sp0, cbuf);

  // GEMM1 + LIF1: sp1 = LIF(sp0 @ w1b^T), buckets [512,1024)
  gemm_lif_kernel<2048, 1024, false><<<512, 256, 0, stream>>>(
      sp0, w1b, cn1, tn1, th1, wn + 2048, sp1, nullptr, cbuf, 512);

  // GEMM2 + LIF2: out = LIF(sp1 @ w2b^T) at t=16, buckets [1024,1280)
  gemm_lif_kernel<1024, 512, true><<<256, 256, 0, stream>>>(
      sp1, w2b, cn2, tn2, th2, wn + 3072, nullptr, out, cbuf, 1024);

  finalize_kernel<<<1, 256, 0, stream>>>(cbuf, out);
}

// Round 8
// 280.282 us; speedup vs baseline: 1.6878x; 1.0381x over previous
//
#include <hip/hip_runtime.h>
#include <math.h>

// NeuromorphicPrivacyNetwork: 3-layer LIF SNN, T=16, B=256, sizes 1024->2048->1024->512.
// Round-14: occupancy + dispatch-count package on top of round-13b (passed, 291us):
//   (a) gemm_lif generalized to tile BM x 64 (BM=128 path bit-identical to r13b's
//       verified GEMM1). GEMM2 now BM=64 -> grid 512 (2 blocks/CU, was 256 = 1/CU,
//       latency-exposed).
//   (b) wnorm + convert + base0 merged into ONE role-split setup dispatch (they are
//       mutually independent; overlap + 2 fewer launch/drain gaps).
//   (c) cbuf 1536 buckets: l0 [0,512), gemm1 [512,1024), gemm2 [1024,1536).
// 5 dispatches: setup, l0, gemm1+lif1, gemm2+lif2(+out), finalize.
// LIF-in-epilogue recurrence (quad-serial + shfl broadcast) unchanged from r13b.

#define T_STEPS 16

typedef short short8 __attribute__((ext_vector_type(8)));
typedef float floatx4 __attribute__((ext_vector_type(4)));

__device__ inline ushort f2bf(float x) {
  unsigned int u = __float_as_uint(x);
  unsigned int r = (u + 0x7FFFu + ((u >> 16) & 1u)) >> 16;
  return (ushort)r;
}
__device__ inline float bf2f(ushort h) {
  return __uint_as_float(((unsigned int)h) << 16);
}
__device__ inline floatx4 mfma16(short8 a, short8 b, floatx4 c) {
  return __builtin_amdgcn_mfma_f32_16x16x32_bf16(a, b, c, 0, 0, 0);
}

// async global->LDS, 16B per lane; dest = wave-uniform base + lane*16
__device__ inline void gload16(const ushort* g, ushort* l) {
  __builtin_amdgcn_global_load_lds(
      (const __attribute__((address_space(1))) void*)g,
      (__attribute__((address_space(3))) void*)l, 16, 0, 0);
}

// stage 16 fp32 -> hi/lo bf16 pairs into LDS (base0 setup GEMM only)
__device__ inline void stage_split16(const float* __restrict__ src, ushort* dsth, ushort* dstl) {
  float fv[16];
  #pragma unroll
  for (int i = 0; i < 4; ++i) *(float4*)&fv[4 * i] = *(const float4*)(src + 4 * i);
  unsigned int ph[8], pl[8];
  #pragma unroll
  for (int i = 0; i < 8; ++i) {
    ushort h0 = f2bf(fv[2 * i]);
    ushort l0 = f2bf(fv[2 * i] - bf2f(h0));
    ushort h1 = f2bf(fv[2 * i + 1]);
    ushort l1 = f2bf(fv[2 * i + 1] - bf2f(h1));
    ph[i] = (unsigned int)h0 | ((unsigned int)h1 << 16);
    pl[i] = (unsigned int)l0 | ((unsigned int)l1 << 16);
  }
  *(uint4*)dsth       = make_uint4(ph[0], ph[1], ph[2], ph[3]);
  *(uint4*)(dsth + 8) = make_uint4(ph[4], ph[5], ph[6], ph[7]);
  *(uint4*)dstl       = make_uint4(pl[0], pl[1], pl[2], pl[3]);
  *(uint4*)(dstl + 8) = make_uint4(pl[4], pl[5], pl[6], pl[7]);
}

// block-reduce then STORE into this block's private bucket (written exactly once).
__device__ inline void cost_store_bucket(float csum, int cnt, float2* __restrict__ cbuf,
                                         int bucket_base) {
  #pragma unroll
  for (int off = 32; off > 0; off >>= 1) {
    csum += __shfl_down(csum, off);
    cnt  += __shfl_down(cnt, off);
  }
  __shared__ float sc[4];
  __shared__ int   si[4];
  int wid = threadIdx.x >> 6;
  if ((threadIdx.x & 63) == 0) { sc[wid] = csum; si[wid] = cnt; }
  __syncthreads();
  if (threadIdx.x == 0) {
    float c = sc[0] + sc[1] + sc[2] + sc[3];
    int   k = si[0] + si[1] + si[2] + si[3];
    float2 v;
    v.x = c * 0.01f;             // per-spike cost = 0.1 * fac/10 * wn = 0.01*fac*wn
    v.y = (float)k;
    cbuf[bucket_base + blockIdx.x] = v;
  }
}

// ---------------- merged setup: wnorm | convert | base0, role by blockIdx ----------------
// bid [0,896): wnorm (4 rows/block); [896,2176): convert W1/W2->bf16; [2176,2304): base0.

__global__ __launch_bounds__(256) void setup_kernel(const float* __restrict__ w0,
                                                    const float* __restrict__ w1,
                                                    const float* __restrict__ w2,
                                                    const float* __restrict__ inputs,
                                                    float* __restrict__ wn,
                                                    ushort* __restrict__ w1b,
                                                    ushort* __restrict__ w2b,
                                                    float* __restrict__ base0C) {
  __shared__ ushort Ah[64][72], Al[64][72], Bh[64][72], Bl[64][72];  // base0 role only
  const int bid = blockIdx.x;
  const int tid = threadIdx.x;

  if (bid < 896) {
    // ---- wnorm: row r = bid*4 + wave, per-wave reduction ----
    int r = bid * 4 + (tid >> 6);
    int lane = tid & 63;
    const float* row; int K;
    if (r < 2048)      { row = w0 + (size_t)r * 1024;          K = 1024; }
    else if (r < 3072) { row = w1 + (size_t)(r - 2048) * 2048; K = 2048; }
    else               { row = w2 + (size_t)(r - 3072) * 1024; K = 1024; }
    float ss = 0.f;
    for (int k = lane; k < K; k += 64) { float x = row[k]; ss += x * x; }
    #pragma unroll
    for (int off = 32; off > 0; off >>= 1) ss += __shfl_down(ss, off);
    if (lane == 0) wn[r] = sqrtf(ss);
    return;
  }
  if (bid < 2176) {
    // ---- convert W1,W2 -> bf16 ----
    int i = ((bid - 896) * 256 + tid) * 8;   // 1280 blocks -> 2621440 elems
    const float* src; ushort* dst;
    if (i < 2097152) { src = w1 + i; dst = w1b + i; }
    else             { src = w2 + (i - 2097152); dst = w2b + (i - 2097152); }
    float4 a = *(const float4*)src;
    float4 b = *(const float4*)(src + 4);
    unsigned int p0 = (unsigned int)f2bf(a.x) | ((unsigned int)f2bf(a.y) << 16);
    unsigned int p1 = (unsigned int)f2bf(a.z) | ((unsigned int)f2bf(a.w) << 16);
    unsigned int p2 = (unsigned int)f2bf(b.x) | ((unsigned int)f2bf(b.y) << 16);
    unsigned int p3 = (unsigned int)f2bf(b.z) | ((unsigned int)f2bf(b.w) << 16);
    *(uint4*)dst = make_uint4(p0, p1, p2, p3);
    return;
  }

  // ---- base0 = inputs @ w0^T via split MFMA (128 blocks; rb = bid-2176) ----
  const int rb = bid - 2176;
  const int m0 = (rb & 3) * 64;
  const int n0 = (rb >> 2) * 64;
  const int lane = tid & 63, wv = tid >> 6;
  const int wm = wv & 1, wn2 = wv >> 1;
  const int l15 = lane & 15, quad = lane >> 4;
  const int sr = tid >> 2, scol = (tid & 3) * 16;

  floatx4 acc[2][2];
  #pragma unroll
  for (int i = 0; i < 2; ++i)
    #pragma unroll
    for (int j = 0; j < 2; ++j) acc[i][j] = (floatx4){0.f, 0.f, 0.f, 0.f};

  for (int k0 = 0; k0 < 1024; k0 += 64) {
    stage_split16(inputs + (size_t)(m0 + sr) * 1024 + k0 + scol, &Ah[sr][scol], &Al[sr][scol]);
    stage_split16(w0 + (size_t)(n0 + sr) * 1024 + k0 + scol, &Bh[sr][scol], &Bl[sr][scol]);
    __syncthreads();
    #pragma unroll
    for (int ks = 0; ks < 2; ++ks) {
      short8 ah[2], al[2], bh[2], bl[2];
      #pragma unroll
      for (int s = 0; s < 2; ++s) {
        ah[s] = *(const short8*)&Ah[32 * wm + 16 * s + l15][ks * 32 + quad * 8];
        al[s] = *(const short8*)&Al[32 * wm + 16 * s + l15][ks * 32 + quad * 8];
        bh[s] = *(const short8*)&Bh[32 * wn2 + 16 * s + l15][ks * 32 + quad * 8];
        bl[s] = *(const short8*)&Bl[32 * wn2 + 16 * s + l15][ks * 32 + quad * 8];
      }
      #pragma unroll
      for (int sm = 0; sm < 2; ++sm)
        #pragma unroll
        for (int sn = 0; sn < 2; ++sn) {
          acc[sm][sn] = mfma16(ah[sm], bh[sn], acc[sm][sn]);
          acc[sm][sn] = mfma16(ah[sm], bl[sn], acc[sm][sn]);
          acc[sm][sn] = mfma16(al[sm], bh[sn], acc[sm][sn]);
        }
    }
    __syncthreads();
  }
  #pragma unroll
  for (int sm = 0; sm < 2; ++sm)
    #pragma unroll
    for (int sn = 0; sn < 2; ++sn)
      #pragma unroll
      for (int r = 0; r < 4; ++r) {
        int m = m0 + 32 * wm + 16 * sm + quad * 4 + r;
        int n = n0 + 32 * wn2 + 16 * sn + l15;
        base0C[(size_t)m * 2048 + n] = acc[sm][sn][r];
      }
}

// ---- fused GEMM + LIF: A[4096][K] (rows m=b*16+t) @ W[N][K]^T, LIF in epilogue ----
// Tile BM x 64, BK=64, 4 waves (each (BM/2) x 32), full K, dbuf LDS.
// BM=128 instantiation is identical to round-13b's verified GEMM1.

template<int K, int N, int BM, bool LAST>
__global__ __launch_bounds__(256) void gemm_lif_kernel(const ushort* __restrict__ A,
                                                       const ushort* __restrict__ W,
                                                       const float* __restrict__ cn,
                                                       const float* __restrict__ tn,
                                                       const float* __restrict__ th,
                                                       const float* __restrict__ wnv,
                                                       ushort* __restrict__ spout,  // [4096][N] (b*16+t rows), null if LAST
                                                       float* __restrict__ outF,    // [256][N] if LAST
                                                       float2* __restrict__ cbuf,
                                                       int bucket_base) {
  __shared__ __attribute__((aligned(16))) ushort As[2][BM * 64];
  __shared__ __attribute__((aligned(16))) ushort Bs[2][64 * 64];
  constexpr int NSTEP = K / 64;
  constexpr int NT = N / 64;           // n-tiles
  constexpr int MT = 4096 / BM;        // m-tiles
  constexpr int NWG = MT * NT;         // 512 both GEMMs, divisible by 8
  constexpr int SM = BM / 32;          // acc rows per wave (4 for BM=128, 2 for BM=64)

  // XCD-bijective swizzle
  const int orig = ((int)blockIdx.x % 8) * (NWG / 8) + (int)blockIdx.x / 8;
  const int m0 = (orig / NT) * BM;
  const int n0 = (orig % NT) * 64;

  const int tid = threadIdx.x;
  const int lane = tid & 63, wv = tid >> 6;
  const int wm = wv & 1, wn2 = wv >> 1;
  const int l15 = lane & 15, quad = lane >> 4;

  const ushort* Ab = A + (size_t)m0 * K;
  const ushort* Wb = W + (size_t)n0 * K;

  const int lrow = lane >> 3;                       // 0..7
  const int lslot = (lane & 7) ^ lrow;              // inverse-swizzled source slot

  floatx4 acc[SM][2];
  #pragma unroll
  for (int i = 0; i < SM; ++i)
    #pragma unroll
    for (int j = 0; j < 2; ++j) acc[i][j] = (floatx4){0.f, 0.f, 0.f, 0.f};

  auto stage = [&](int buf, int k0) {
    #pragma unroll
    for (int h = 0; h < SM; ++h) {                   // A: BM rows = 4 waves x SM x 8
      int r0 = wv * (BM / 4) + h * 8;
      gload16(Ab + (size_t)(r0 + lrow) * K + k0 + lslot * 8, &As[buf][r0 * 64]);
    }
    #pragma unroll
    for (int h = 0; h < 2; ++h) {                    // B: 64 rows = 4 waves x 2 x 8
      int r0 = wv * 16 + h * 8;
      gload16(Wb + (size_t)(r0 + lrow) * K + k0 + lslot * 8, &Bs[buf][r0 * 64]);
    }
  };
  auto compute = [&](int buf) {
    #pragma unroll
    for (int ks = 0; ks < 2; ++ks) {
      short8 af[SM], bf[2];
      #pragma unroll
      for (int s = 0; s < SM; ++s) {
        int arow = wm * (BM / 2) + s * 16 + l15;
        af[s] = *(const short8*)&As[buf][arow * 64 + (((ks * 4 + quad) ^ (arow & 7)) << 3)];
      }
      #pragma unroll
      for (int s = 0; s < 2; ++s) {
        int brow = wn2 * 32 + s * 16 + l15;
        bf[s] = *(const short8*)&Bs[buf][brow * 64 + (((ks * 4 + quad) ^ (brow & 7)) << 3)];
      }
      #pragma unroll
      for (int sm = 0; sm < SM; ++sm)
        #pragma unroll
        for (int sn = 0; sn < 2; ++sn)
          acc[sm][sn] = mfma16(af[sm], bf[sn], acc[sm][sn]);
    }
  };

  stage(0, 0);
  __syncthreads();
  for (int kk = 0; kk < NSTEP; ++kk) {
    int buf = kk & 1;
    if (kk + 1 < NSTEP) stage(buf ^ 1, (kk + 1) * 64);
    compute(buf);
    __syncthreads();
  }

  // ---- epilogue: in-register LIF over t, serialized across quads ----
  // Thread owns C[m][n], m = m0 + wm*(BM/2) + sm*16 + quad*4 + r, n = n0 + wn2*32 + sn*16 + l15.
  // Row m = b*16 + (t-1): b = m>>4 (per-sm constant), t-1 = quad*4+r (thread-local).
  float csum = 0.f; int cnt = 0;
  #pragma unroll
  for (int sm = 0; sm < SM; ++sm) {
    const int b = (m0 >> 4) + wm * SM + sm;
    #pragma unroll
    for (int sn = 0; sn < 2; ++sn) {
      const int n = n0 + wn2 * 32 + sn * 16 + l15;
      float cnv[4], tnv[4];
      #pragma unroll
      for (int r = 0; r < 4; ++r) {
        size_t off = (size_t)(quad * 4 + r) * (256 * N) + (size_t)b * N + n;
        cnv[r] = cn[off];
        tnv[r] = tn[off];
      }
      const float thn = th[n];
      const float wnn = wnv[n];
      float V = 0.f; int prev = 0;
      ushort skeep[4] = {0, 0, 0, 0};
      #pragma unroll
      for (int qq = 0; qq < 4; ++qq) {
        float Vl = V; int pl = prev;
        ushort slocal[4];
        #pragma unroll
        for (int r = 0; r < 4; ++r) {
          float cur = acc[sm][sn][r] + cnv[r] * (0.05f * wnn);
          float Vn = pl ? Vl : (0.95f * Vl + cur);
          float thr = thn + tnv[r] * 0.1f;
          bool sp = (!pl) && (Vn > thr);
          Vl = sp ? 0.f : Vn;
          slocal[r] = sp ? (ushort)0x3F80 : (ushort)0;
          pl = sp ? 1 : 0;
        }
        if (quad == qq) {
          #pragma unroll
          for (int r = 0; r < 4; ++r) skeep[r] = slocal[r];
        }
        V = __shfl(Vl, l15 + (qq << 4));
        prev = __shfl(pl, l15 + (qq << 4));
      }
      #pragma unroll
      for (int r = 0; r < 4; ++r) {
        int t = quad * 4 + r + 1;
        float f = (t <= 7) ? 10.f : (float)(17 - t);
        if (skeep[r]) { csum += wnn * f; cnt++; }
      }
      if (!LAST) {
        const int mbase = m0 + wm * (BM / 2) + sm * 16 + quad * 4;
        #pragma unroll
        for (int r = 0; r < 4; ++r)
          spout[(size_t)(mbase + r) * N + n] = skeep[r];
      } else {
        if (quad == 3) outF[(size_t)b * N + n] = skeep[3] ? 1.f : 0.f;  // t=16
      }
    }
  }
  cost_store_bucket(csum, cnt, cbuf, bucket_base);
}

// ---------------- L0 LIF: all 16 steps, state in registers ----------------
// 512 blocks x 256 threads x 4 elems; sp0 written in m = b*16 + (t-1) row layout.

__global__ __launch_bounds__(256) void l0_lif_kernel(const float* __restrict__ base0,
                                                     const float* __restrict__ cn0,
                                                     const float* __restrict__ tn0,
                                                     const float* __restrict__ th0,
                                                     const float* __restrict__ wn0,
                                                     ushort* __restrict__ sp0,
                                                     float2* __restrict__ cbuf) {
  const int e = (blockIdx.x * 256 + threadIdx.x) * 4;
  const int n = e & 2047;
  const int b = e >> 11;
  float4 bb  = *(const float4*)(base0 + e);
  float4 th4 = *(const float4*)(th0 + n);
  float4 wn4 = *(const float4*)(wn0 + n);
  float bbv[4] = {bb.x, bb.y, bb.z, bb.w};
  float thv[4] = {th4.x, th4.y, th4.z, th4.w};
  float wnq[4] = {wn4.x, wn4.y, wn4.z, wn4.w};
  float V[4] = {0.f, 0.f, 0.f, 0.f};
  bool prev[4] = {false, false, false, false};
  float csum = 0.f; int cnt = 0;
  #pragma unroll 2
  for (int t = 1; t <= T_STEPS; ++t) {
    size_t off = (size_t)(t - 1) * 524288 + e;
    float4 c4 = *(const float4*)(cn0 + off);
    float4 t4 = *(const float4*)(tn0 + off);
    float cnv[4] = {c4.x, c4.y, c4.z, c4.w};
    float tnv[4] = {t4.x, t4.y, t4.z, t4.w};
    float f = (t <= 7) ? 10.f : (float)(17 - t);
    ushort sout[4];
    #pragma unroll
    for (int j = 0; j < 4; ++j) {
      float cur = bbv[j] + cnv[j] * (0.05f * wnq[j]);
      float Vn = prev[j] ? V[j] : (0.95f * V[j] + cur);
      float thr = thv[j] + tnv[j] * 0.1f;
      bool sp = (!prev[j]) && (Vn > thr);
      V[j] = sp ? 0.f : Vn;
      sout[j] = sp ? (ushort)0x3F80 : (ushort)0;
      prev[j] = sp;
      if (sp) { csum += wnq[j] * f; cnt++; }
    }
    ushort4 sq; sq.x = sout[0]; sq.y = sout[1]; sq.z = sout[2]; sq.w = sout[3];
    *(ushort4*)(sp0 + (size_t)(b * 16 + t - 1) * 2048 + n) = sq;
  }
  cost_store_bucket(csum, cnt, cbuf, 0);
}

// ---------------- finalize: reduce 1536 buckets -> cost, entropy ----------------

__global__ __launch_bounds__(256) void finalize_kernel(const float2* __restrict__ cbuf,
                                                       float* __restrict__ out) {
  float c = 0.f, k = 0.f;
  for (int i = threadIdx.x; i < 1536; i += 256) {
    float2 v = cbuf[i];
    c += v.x; k += v.y;
  }
  #pragma unroll
  for (int off = 32; off > 0; off >>= 1) {
    c += __shfl_down(c, off);
    k += __shfl_down(k, off);
  }
  __shared__ float sc[4], sk[4];
  int wid = threadIdx.x >> 6;
  if ((threadIdx.x & 63) == 0) { sc[wid] = c; sk[wid] = k; }
  __syncthreads();
  if (threadIdx.x == 0) {
    float cost = sc[0] + sc[1] + sc[2] + sc[3];
    float tot  = sk[0] + sk[1] + sk[2] + sk[3];
    float p1 = tot / 14680064.f;   // T*B*(2048+1024+512)
    float p0 = 1.f - p1;
    float ent = -(p1 * log2f(p1 + 1e-12f) + p0 * log2f(p0 + 1e-12f));
    out[131072] = cost;
    out[131073] = ent;
  }
}

// ---------------- launch ----------------

extern "C" void kernel_launch(void* const* d_in, const int* in_sizes, int n_in,
                              void* d_out, int out_size, void* d_ws, size_t ws_size,
                              hipStream_t stream) {
  const float* inputs = (const float*)d_in[0];
  const float* w0  = (const float*)d_in[1];
  const float* th0 = (const float*)d_in[2];
  const float* cn0 = (const float*)d_in[3];
  const float* tn0 = (const float*)d_in[4];
  const float* w1  = (const float*)d_in[5];
  const float* th1 = (const float*)d_in[6];
  const float* cn1 = (const float*)d_in[7];
  const float* tn1 = (const float*)d_in[8];
  const float* w2  = (const float*)d_in[9];
  const float* th2 = (const float*)d_in[10];
  const float* cn2 = (const float*)d_in[11];
  const float* tn2 = (const float*)d_in[12];
  float* out = (float*)d_out;
  float* ws  = (float*)d_ws;

  // workspace layout (float slots), ~35 MB total
  float* wn    = ws;                        // 4096 (3584 used)
  float* base0 = ws + 4096;                 // 524288 fp32 [256][2048]
  ushort* w1b  = (ushort*)(base0 + 524288); // 2097152 ushort [1024][2048]
  ushort* w2b  = w1b + 2097152;             // 524288 ushort [512][1024]
  ushort* sp0  = w2b + 524288;              // 8388608 ushort [4096][2048] (m=b*16+t)
  ushort* sp1  = sp0 + 8388608;             // 4194304 ushort [4096][1024] (m=b*16+t)
  float2* cbuf = (float2*)(sp1 + 4194304);  // 1536 float2

  // setup: wnorm (896) | convert (1280) | base0 (128) = 2304 blocks
  setup_kernel<<<2304, 256, 0, stream>>>(w0, w1, w2, inputs, wn, w1b, w2b, base0);

  // L0: all 16 steps -> sp0 (b*16+t layout), buckets [0,512)
  l0_lif_kernel<<<512, 256, 0, stream>>>(base0, cn0, tn0, th0, wn, sp0, cbuf);

  // GEMM1 + LIF1 (tile 128x64, 512 blocks): sp1 = LIF(sp0 @ w1b^T), buckets [512,1024)
  gemm_lif_kernel<2048, 1024, 128, false><<<512, 256, 0, stream>>>(
      sp0, w1b, cn1, tn1, th1, wn + 2048, sp1, nullptr, cbuf, 512);

  // GEMM2 + LIF2 (tile 64x64, 512 blocks, 2/CU): out = LIF(sp1 @ w2b^T) at t=16,
  // buckets [1024,1536)
  gemm_lif_kernel<1024, 512, 64, true><<<512, 256, 0, stream>>>(
      sp1, w2b, cn2, tn2, th2, wn + 3072, nullptr, out, cbuf, 1024);

  finalize_kernel<<<1, 256, 0, stream>>>(cbuf, out);
}

// Round 9
// 258.624 us; speedup vs baseline: 1.8292x; 1.0837x over previous
//
#include <hip/hip_runtime.h>
#include <math.h>

// NeuromorphicPrivacyNetwork: 3-layer LIF SNN, T=16, B=256, sizes 1024->2048->1024->512.
// Round-15: fix setup_kernel (54us, MfmaUtil 2%, 0.7TB/s in round-14 counters).
// Root cause: base0 role was scheduled LAST (bids 2176+) -> started after ~2000 blocks
// retired, then ran ~35us serial-K single-buffered on only 128 CUs.
// Fix: (a) base0 FIRST (bids 0-511); (b) base0 K-split 4 -> 512 blocks x 4 K-iters,
// fp32 partials P0[4][256][2048]; whole chip busy, TLP (4 blocks/CU) hides load latency;
// (c) l0 sums the 4 partial slices (+6MB reads on an HBM-bound kernel, ~+1us).
// Everything else verbatim from round-14 (passed, 280us):
//   gemm_lif BMx64 fused GEMM+LIF (BM=128 GEMM1 / BM=64 GEMM2, both 512 blocks),
//   m=b*16+t spike layout, quad-serial LIF epilogue, gload_lds + src-side swizzle,
//   XCD-bijective block swizzle, 1536 one-shot cost buckets.
// 5 dispatches: setup, l0, gemm1+lif1, gemm2+lif2(+out), finalize.

#define T_STEPS 16

typedef short short8 __attribute__((ext_vector_type(8)));
typedef float floatx4 __attribute__((ext_vector_type(4)));

__device__ inline ushort f2bf(float x) {
  unsigned int u = __float_as_uint(x);
  unsigned int r = (u + 0x7FFFu + ((u >> 16) & 1u)) >> 16;
  return (ushort)r;
}
__device__ inline float bf2f(ushort h) {
  return __uint_as_float(((unsigned int)h) << 16);
}
__device__ inline floatx4 mfma16(short8 a, short8 b, floatx4 c) {
  return __builtin_amdgcn_mfma_f32_16x16x32_bf16(a, b, c, 0, 0, 0);
}

// async global->LDS, 16B per lane; dest = wave-uniform base + lane*16
__device__ inline void gload16(const ushort* g, ushort* l) {
  __builtin_amdgcn_global_load_lds(
      (const __attribute__((address_space(1))) void*)g,
      (__attribute__((address_space(3))) void*)l, 16, 0, 0);
}

// stage 16 fp32 -> hi/lo bf16 pairs into LDS (base0 role only)
__device__ inline void stage_split16(const float* __restrict__ src, ushort* dsth, ushort* dstl) {
  float fv[16];
  #pragma unroll
  for (int i = 0; i < 4; ++i) *(float4*)&fv[4 * i] = *(const float4*)(src + 4 * i);
  unsigned int ph[8], pl[8];
  #pragma unroll
  for (int i = 0; i < 8; ++i) {
    ushort h0 = f2bf(fv[2 * i]);
    ushort l0 = f2bf(fv[2 * i] - bf2f(h0));
    ushort h1 = f2bf(fv[2 * i + 1]);
    ushort l1 = f2bf(fv[2 * i + 1] - bf2f(h1));
    ph[i] = (unsigned int)h0 | ((unsigned int)h1 << 16);
    pl[i] = (unsigned int)l0 | ((unsigned int)l1 << 16);
  }
  *(uint4*)dsth       = make_uint4(ph[0], ph[1], ph[2], ph[3]);
  *(uint4*)(dsth + 8) = make_uint4(ph[4], ph[5], ph[6], ph[7]);
  *(uint4*)dstl       = make_uint4(pl[0], pl[1], pl[2], pl[3]);
  *(uint4*)(dstl + 8) = make_uint4(pl[4], pl[5], pl[6], pl[7]);
}

// block-reduce then STORE into this block's private bucket (written exactly once).
__device__ inline void cost_store_bucket(float csum, int cnt, float2* __restrict__ cbuf,
                                         int bucket_base) {
  #pragma unroll
  for (int off = 32; off > 0; off >>= 1) {
    csum += __shfl_down(csum, off);
    cnt  += __shfl_down(cnt, off);
  }
  __shared__ float sc[4];
  __shared__ int   si[4];
  int wid = threadIdx.x >> 6;
  if ((threadIdx.x & 63) == 0) { sc[wid] = csum; si[wid] = cnt; }
  __syncthreads();
  if (threadIdx.x == 0) {
    float c = sc[0] + sc[1] + sc[2] + sc[3];
    int   k = si[0] + si[1] + si[2] + si[3];
    float2 v;
    v.x = c * 0.01f;             // per-spike cost = 0.1 * fac/10 * wn = 0.01*fac*wn
    v.y = (float)k;
    cbuf[bucket_base + blockIdx.x] = v;
  }
}

// ---------------- merged setup: base0(K-split) | wnorm | convert ----------------
// bid [0,512):      base0 partial GEMM (m-tile 4 x n-tile 32 x kslice 4)
// bid [512,1408):   wnorm (4 rows/block)
// bid [1408,2688):  convert W1/W2 -> bf16

__global__ __launch_bounds__(256) void setup_kernel(const float* __restrict__ w0,
                                                    const float* __restrict__ w1,
                                                    const float* __restrict__ w2,
                                                    const float* __restrict__ inputs,
                                                    float* __restrict__ wn,
                                                    ushort* __restrict__ w1b,
                                                    ushort* __restrict__ w2b,
                                                    float* __restrict__ P0) {  // [4][256][2048]
  __shared__ ushort Ah[64][72], Al[64][72], Bh[64][72], Bl[64][72];  // base0 role only
  const int bid = blockIdx.x;
  const int tid = threadIdx.x;

  if (bid >= 1408) {
    // ---- convert W1,W2 -> bf16 ----
    int i = ((bid - 1408) * 256 + tid) * 8;   // 1280 blocks -> 2621440 elems
    const float* src; ushort* dst;
    if (i < 2097152) { src = w1 + i; dst = w1b + i; }
    else             { src = w2 + (i - 2097152); dst = w2b + (i - 2097152); }
    float4 a = *(const float4*)src;
    float4 b = *(const float4*)(src + 4);
    unsigned int p0 = (unsigned int)f2bf(a.x) | ((unsigned int)f2bf(a.y) << 16);
    unsigned int p1 = (unsigned int)f2bf(a.z) | ((unsigned int)f2bf(a.w) << 16);
    unsigned int p2 = (unsigned int)f2bf(b.x) | ((unsigned int)f2bf(b.y) << 16);
    unsigned int p3 = (unsigned int)f2bf(b.z) | ((unsigned int)f2bf(b.w) << 16);
    *(uint4*)dst = make_uint4(p0, p1, p2, p3);
    return;
  }
  if (bid >= 512) {
    // ---- wnorm: row r = (bid-512)*4 + wave, per-wave reduction ----
    int r = (bid - 512) * 4 + (tid >> 6);
    int lane = tid & 63;
    const float* row; int K;
    if (r < 2048)      { row = w0 + (size_t)r * 1024;          K = 1024; }
    else if (r < 3072) { row = w1 + (size_t)(r - 2048) * 2048; K = 2048; }
    else               { row = w2 + (size_t)(r - 3072) * 1024; K = 1024; }
    float ss = 0.f;
    for (int k = lane; k < K; k += 64) { float x = row[k]; ss += x * x; }
    #pragma unroll
    for (int off = 32; off > 0; off >>= 1) ss += __shfl_down(ss, off);
    if (lane == 0) wn[r] = sqrtf(ss);
    return;
  }

  // ---- base0 partial: P0[sl] += inputs[:, ks] @ w0[:, ks]^T (split MFMA) ----
  const int m0 = (bid & 3) * 64;
  const int n0 = ((bid >> 2) & 31) * 64;
  const int sl = bid >> 7;                 // 0..3
  const int kbase = sl * 256;
  const int lane = tid & 63, wv = tid >> 6;
  const int wm = wv & 1, wn2 = wv >> 1;
  const int l15 = lane & 15, quad = lane >> 4;
  const int sr = tid >> 2, scol = (tid & 3) * 16;

  floatx4 acc[2][2];
  #pragma unroll
  for (int i = 0; i < 2; ++i)
    #pragma unroll
    for (int j = 0; j < 2; ++j) acc[i][j] = (floatx4){0.f, 0.f, 0.f, 0.f};

  for (int k0 = 0; k0 < 256; k0 += 64) {
    stage_split16(inputs + (size_t)(m0 + sr) * 1024 + kbase + k0 + scol, &Ah[sr][scol], &Al[sr][scol]);
    stage_split16(w0 + (size_t)(n0 + sr) * 1024 + kbase + k0 + scol, &Bh[sr][scol], &Bl[sr][scol]);
    __syncthreads();
    #pragma unroll
    for (int ks = 0; ks < 2; ++ks) {
      short8 ah[2], al[2], bh[2], bl[2];
      #pragma unroll
      for (int s = 0; s < 2; ++s) {
        ah[s] = *(const short8*)&Ah[32 * wm + 16 * s + l15][ks * 32 + quad * 8];
        al[s] = *(const short8*)&Al[32 * wm + 16 * s + l15][ks * 32 + quad * 8];
        bh[s] = *(const short8*)&Bh[32 * wn2 + 16 * s + l15][ks * 32 + quad * 8];
        bl[s] = *(const short8*)&Bl[32 * wn2 + 16 * s + l15][ks * 32 + quad * 8];
      }
      #pragma unroll
      for (int sm = 0; sm < 2; ++sm)
        #pragma unroll
        for (int sn = 0; sn < 2; ++sn) {
          acc[sm][sn] = mfma16(ah[sm], bh[sn], acc[sm][sn]);
          acc[sm][sn] = mfma16(ah[sm], bl[sn], acc[sm][sn]);
          acc[sm][sn] = mfma16(al[sm], bh[sn], acc[sm][sn]);
        }
    }
    __syncthreads();
  }
  float* Ps = P0 + (size_t)sl * 524288;
  #pragma unroll
  for (int sm = 0; sm < 2; ++sm)
    #pragma unroll
    for (int sn = 0; sn < 2; ++sn)
      #pragma unroll
      for (int r = 0; r < 4; ++r) {
        int m = m0 + 32 * wm + 16 * sm + quad * 4 + r;
        int n = n0 + 32 * wn2 + 16 * sn + l15;
        Ps[(size_t)m * 2048 + n] = acc[sm][sn][r];
      }
}

// ---- fused GEMM + LIF: A[4096][K] (rows m=b*16+t) @ W[N][K]^T, LIF in epilogue ----
// Tile BM x 64, BK=64, 4 waves (each (BM/2) x 32), full K, dbuf LDS.

template<int K, int N, int BM, bool LAST>
__global__ __launch_bounds__(256) void gemm_lif_kernel(const ushort* __restrict__ A,
                                                       const ushort* __restrict__ W,
                                                       const float* __restrict__ cn,
                                                       const float* __restrict__ tn,
                                                       const float* __restrict__ th,
                                                       const float* __restrict__ wnv,
                                                       ushort* __restrict__ spout,  // [4096][N] (b*16+t rows), null if LAST
                                                       float* __restrict__ outF,    // [256][N] if LAST
                                                       float2* __restrict__ cbuf,
                                                       int bucket_base) {
  __shared__ __attribute__((aligned(16))) ushort As[2][BM * 64];
  __shared__ __attribute__((aligned(16))) ushort Bs[2][64 * 64];
  constexpr int NSTEP = K / 64;
  constexpr int NT = N / 64;           // n-tiles
  constexpr int MT = 4096 / BM;        // m-tiles
  constexpr int NWG = MT * NT;         // 512 both GEMMs, divisible by 8
  constexpr int SM = BM / 32;          // acc rows per wave (4 for BM=128, 2 for BM=64)

  // XCD-bijective swizzle
  const int orig = ((int)blockIdx.x % 8) * (NWG / 8) + (int)blockIdx.x / 8;
  const int m0 = (orig / NT) * BM;
  const int n0 = (orig % NT) * 64;

  const int tid = threadIdx.x;
  const int lane = tid & 63, wv = tid >> 6;
  const int wm = wv & 1, wn2 = wv >> 1;
  const int l15 = lane & 15, quad = lane >> 4;

  const ushort* Ab = A + (size_t)m0 * K;
  const ushort* Wb = W + (size_t)n0 * K;

  const int lrow = lane >> 3;                       // 0..7
  const int lslot = (lane & 7) ^ lrow;              // inverse-swizzled source slot

  floatx4 acc[SM][2];
  #pragma unroll
  for (int i = 0; i < SM; ++i)
    #pragma unroll
    for (int j = 0; j < 2; ++j) acc[i][j] = (floatx4){0.f, 0.f, 0.f, 0.f};

  auto stage = [&](int buf, int k0) {
    #pragma unroll
    for (int h = 0; h < SM; ++h) {                   // A: BM rows = 4 waves x SM x 8
      int r0 = wv * (BM / 4) + h * 8;
      gload16(Ab + (size_t)(r0 + lrow) * K + k0 + lslot * 8, &As[buf][r0 * 64]);
    }
    #pragma unroll
    for (int h = 0; h < 2; ++h) {                    // B: 64 rows = 4 waves x 2 x 8
      int r0 = wv * 16 + h * 8;
      gload16(Wb + (size_t)(r0 + lrow) * K + k0 + lslot * 8, &Bs[buf][r0 * 64]);
    }
  };
  auto compute = [&](int buf) {
    #pragma unroll
    for (int ks = 0; ks < 2; ++ks) {
      short8 af[SM], bf[2];
      #pragma unroll
      for (int s = 0; s < SM; ++s) {
        int arow = wm * (BM / 2) + s * 16 + l15;
        af[s] = *(const short8*)&As[buf][arow * 64 + (((ks * 4 + quad) ^ (arow & 7)) << 3)];
      }
      #pragma unroll
      for (int s = 0; s < 2; ++s) {
        int brow = wn2 * 32 + s * 16 + l15;
        bf[s] = *(const short8*)&Bs[buf][brow * 64 + (((ks * 4 + quad) ^ (brow & 7)) << 3)];
      }
      #pragma unroll
      for (int sm = 0; sm < SM; ++sm)
        #pragma unroll
        for (int sn = 0; sn < 2; ++sn)
          acc[sm][sn] = mfma16(af[sm], bf[sn], acc[sm][sn]);
    }
  };

  stage(0, 0);
  __syncthreads();
  for (int kk = 0; kk < NSTEP; ++kk) {
    int buf = kk & 1;
    if (kk + 1 < NSTEP) stage(buf ^ 1, (kk + 1) * 64);
    compute(buf);
    __syncthreads();
  }

  // ---- epilogue: in-register LIF over t, serialized across quads ----
  float csum = 0.f; int cnt = 0;
  #pragma unroll
  for (int sm = 0; sm < SM; ++sm) {
    const int b = (m0 >> 4) + wm * SM + sm;
    #pragma unroll
    for (int sn = 0; sn < 2; ++sn) {
      const int n = n0 + wn2 * 32 + sn * 16 + l15;
      float cnv[4], tnv[4];
      #pragma unroll
      for (int r = 0; r < 4; ++r) {
        size_t off = (size_t)(quad * 4 + r) * (256 * N) + (size_t)b * N + n;
        cnv[r] = cn[off];
        tnv[r] = tn[off];
      }
      const float thn = th[n];
      const float wnn = wnv[n];
      float V = 0.f; int prev = 0;
      ushort skeep[4] = {0, 0, 0, 0};
      #pragma unroll
      for (int qq = 0; qq < 4; ++qq) {
        float Vl = V; int pl = prev;
        ushort slocal[4];
        #pragma unroll
        for (int r = 0; r < 4; ++r) {
          float cur = acc[sm][sn][r] + cnv[r] * (0.05f * wnn);
          float Vn = pl ? Vl : (0.95f * Vl + cur);
          float thr = thn + tnv[r] * 0.1f;
          bool sp = (!pl) && (Vn > thr);
          Vl = sp ? 0.f : Vn;
          slocal[r] = sp ? (ushort)0x3F80 : (ushort)0;
          pl = sp ? 1 : 0;
        }
        if (quad == qq) {
          #pragma unroll
          for (int r = 0; r < 4; ++r) skeep[r] = slocal[r];
        }
        V = __shfl(Vl, l15 + (qq << 4));
        prev = __shfl(pl, l15 + (qq << 4));
      }
      #pragma unroll
      for (int r = 0; r < 4; ++r) {
        int t = quad * 4 + r + 1;
        float f = (t <= 7) ? 10.f : (float)(17 - t);
        if (skeep[r]) { csum += wnn * f; cnt++; }
      }
      if (!LAST) {
        const int mbase = m0 + wm * (BM / 2) + sm * 16 + quad * 4;
        #pragma unroll
        for (int r = 0; r < 4; ++r)
          spout[(size_t)(mbase + r) * N + n] = skeep[r];
      } else {
        if (quad == 3) outF[(size_t)b * N + n] = skeep[3] ? 1.f : 0.f;  // t=16
      }
    }
  }
  cost_store_bucket(csum, cnt, cbuf, bucket_base);
}

// ---------------- L0 LIF: all 16 steps, state in registers ----------------
// 512 blocks x 256 threads x 4 elems; sums 4 base0 partial slices;
// sp0 written in m = b*16 + (t-1) row layout.

__global__ __launch_bounds__(256) void l0_lif_kernel(const float* __restrict__ P0,  // [4][256][2048]
                                                     const float* __restrict__ cn0,
                                                     const float* __restrict__ tn0,
                                                     const float* __restrict__ th0,
                                                     const float* __restrict__ wn0,
                                                     ushort* __restrict__ sp0,
                                                     float2* __restrict__ cbuf) {
  const int e = (blockIdx.x * 256 + threadIdx.x) * 4;
  const int n = e & 2047;
  const int b = e >> 11;
  float4 b0 = *(const float4*)(P0 + e);
  float4 b1 = *(const float4*)(P0 + 524288 + e);
  float4 b2 = *(const float4*)(P0 + 1048576 + e);
  float4 b3 = *(const float4*)(P0 + 1572864 + e);
  float4 th4 = *(const float4*)(th0 + n);
  float4 wn4 = *(const float4*)(wn0 + n);
  float bbv[4] = {b0.x + b1.x + b2.x + b3.x, b0.y + b1.y + b2.y + b3.y,
                  b0.z + b1.z + b2.z + b3.z, b0.w + b1.w + b2.w + b3.w};
  float thv[4] = {th4.x, th4.y, th4.z, th4.w};
  float wnq[4] = {wn4.x, wn4.y, wn4.z, wn4.w};
  float V[4] = {0.f, 0.f, 0.f, 0.f};
  bool prev[4] = {false, false, false, false};
  float csum = 0.f; int cnt = 0;
  #pragma unroll 2
  for (int t = 1; t <= T_STEPS; ++t) {
    size_t off = (size_t)(t - 1) * 524288 + e;
    float4 c4 = *(const float4*)(cn0 + off);
    float4 t4 = *(const float4*)(tn0 + off);
    float cnv[4] = {c4.x, c4.y, c4.z, c4.w};
    float tnv[4] = {t4.x, t4.y, t4.z, t4.w};
    float f = (t <= 7) ? 10.f : (float)(17 - t);
    ushort sout[4];
    #pragma unroll
    for (int j = 0; j < 4; ++j) {
      float cur = bbv[j] + cnv[j] * (0.05f * wnq[j]);
      float Vn = prev[j] ? V[j] : (0.95f * V[j] + cur);
      float thr = thv[j] + tnv[j] * 0.1f;
      bool sp = (!prev[j]) && (Vn > thr);
      V[j] = sp ? 0.f : Vn;
      sout[j] = sp ? (ushort)0x3F80 : (ushort)0;
      prev[j] = sp;
      if (sp) { csum += wnq[j] * f; cnt++; }
    }
    ushort4 sq; sq.x = sout[0]; sq.y = sout[1]; sq.z = sout[2]; sq.w = sout[3];
    *(ushort4*)(sp0 + (size_t)(b * 16 + t - 1) * 2048 + n) = sq;
  }
  cost_store_bucket(csum, cnt, cbuf, 0);
}

// ---------------- finalize: reduce 1536 buckets -> cost, entropy ----------------

__global__ __launch_bounds__(256) void finalize_kernel(const float2* __restrict__ cbuf,
                                                       float* __restrict__ out) {
  float c = 0.f, k = 0.f;
  for (int i = threadIdx.x; i < 1536; i += 256) {
    float2 v = cbuf[i];
    c += v.x; k += v.y;
  }
  #pragma unroll
  for (int off = 32; off > 0; off >>= 1) {
    c += __shfl_down(c, off);
    k += __shfl_down(k, off);
  }
  __shared__ float sc[4], sk[4];
  int wid = threadIdx.x >> 6;
  if ((threadIdx.x & 63) == 0) { sc[wid] = c; sk[wid] = k; }
  __syncthreads();
  if (threadIdx.x == 0) {
    float cost = sc[0] + sc[1] + sc[2] + sc[3];
    float tot  = sk[0] + sk[1] + sk[2] + sk[3];
    float p1 = tot / 14680064.f;   // T*B*(2048+1024+512)
    float p0 = 1.f - p1;
    float ent = -(p1 * log2f(p1 + 1e-12f) + p0 * log2f(p0 + 1e-12f));
    out[131072] = cost;
    out[131073] = ent;
  }
}

// ---------------- launch ----------------

extern "C" void kernel_launch(void* const* d_in, const int* in_sizes, int n_in,
                              void* d_out, int out_size, void* d_ws, size_t ws_size,
                              hipStream_t stream) {
  const float* inputs = (const float*)d_in[0];
  const float* w0  = (const float*)d_in[1];
  const float* th0 = (const float*)d_in[2];
  const float* cn0 = (const float*)d_in[3];
  const float* tn0 = (const float*)d_in[4];
  const float* w1  = (const float*)d_in[5];
  const float* th1 = (const float*)d_in[6];
  const float* cn1 = (const float*)d_in[7];
  const float* tn1 = (const float*)d_in[8];
  const float* w2  = (const float*)d_in[9];
  const float* th2 = (const float*)d_in[10];
  const float* cn2 = (const float*)d_in[11];
  const float* tn2 = (const float*)d_in[12];
  float* out = (float*)d_out;
  float* ws  = (float*)d_ws;

  // workspace layout (float slots), ~41 MB total
  float* wn    = ws;                        // 4096 (3584 used)
  float* P0    = ws + 4096;                 // 2097152 fp32 [4][256][2048] (8 MB)
  ushort* w1b  = (ushort*)(P0 + 2097152);   // 2097152 ushort [1024][2048]
  ushort* w2b  = w1b + 2097152;             // 524288 ushort [512][1024]
  ushort* sp0  = w2b + 524288;              // 8388608 ushort [4096][2048] (m=b*16+t)
  ushort* sp1  = sp0 + 8388608;             // 4194304 ushort [4096][1024] (m=b*16+t)
  float2* cbuf = (float2*)(sp1 + 4194304);  // 1536 float2

  // setup: base0 K-split (512) | wnorm (896) | convert (1280) = 2688 blocks
  setup_kernel<<<2688, 256, 0, stream>>>(w0, w1, w2, inputs, wn, w1b, w2b, P0);

  // L0: all 16 steps (sums 4 P0 slices) -> sp0 (b*16+t layout), buckets [0,512)
  l0_lif_kernel<<<512, 256, 0, stream>>>(P0, cn0, tn0, th0, wn, sp0, cbuf);

  // GEMM1 + LIF1 (tile 128x64, 512 blocks): sp1 = LIF(sp0 @ w1b^T), buckets [512,1024)
  gemm_lif_kernel<2048, 1024, 128, false><<<512, 256, 0, stream>>>(
      sp0, w1b, cn1, tn1, th1, wn + 2048, sp1, nullptr, cbuf, 512);

  // GEMM2 + LIF2 (tile 64x64, 512 blocks): out = LIF(sp1 @ w2b^T) at t=16,
  // buckets [1024,1536)
  gemm_lif_kernel<1024, 512, 64, true><<<512, 256, 0, stream>>>(
      sp1, w2b, cn2, tn2, th2, wn + 3072, nullptr, out, cbuf, 1024);

  finalize_kernel<<<1, 256, 0, stream>>>(cbuf, out);
}

// Round 10
// 238.153 us; speedup vs baseline: 1.9864x; 1.0860x over previous
//
#include <hip/hip_runtime.h>
#include <math.h>

// NeuromorphicPrivacyNetwork: 3-layer LIF SNN, T=16, B=256, sizes 1024->2048->1024->512.
// Round-16: counted-vmcnt depth-2 pipeline in gemm_lif (T4). Round-9 counters showed
// GEMM1 = 55.5us with ~4150 cy/K-step vs ~400 cy of work: __syncthreads() emits
// s_waitcnt vmcnt(0) which DRAINS the just-issued prefetch every step (the documented
// m97-structure stall). Fix: raw s_barrier + counted s_waitcnt vmcnt(N):
//   S(0); S(1);
//   iter kk: vmcnt(LW) [oldest stage landed] ; s_barrier ; compute(buf) ;
//            s_barrier ; S(kk+2 -> buf)   // overwrite only after all waves computed buf
// LW = loads/wave/stage = SM+2 (6 for BM=128, 4 for BM=64); last iter waits vmcnt(0).
// Loads now stay in flight a FULL iteration (depth 2, never drained mid-loop).
// Everything else verbatim from round-15 (passed, 259us): setup (base0-first K-split4),
// l0 (sums 4 P0 slices), fused LIF epilogue, gload_lds + src-swizzle, XCD swizzle.
// 5 dispatches: setup, l0, gemm1+lif1, gemm2+lif2(+out), finalize.

#define T_STEPS 16

typedef short short8 __attribute__((ext_vector_type(8)));
typedef float floatx4 __attribute__((ext_vector_type(4)));

#define SBARRIER() asm volatile("s_barrier" ::: "memory")
#define WAITCNT_VM(N) asm volatile("s_waitcnt vmcnt(" #N ")" ::: "memory")

__device__ inline ushort f2bf(float x) {
  unsigned int u = __float_as_uint(x);
  unsigned int r = (u + 0x7FFFu + ((u >> 16) & 1u)) >> 16;
  return (ushort)r;
}
__device__ inline float bf2f(ushort h) {
  return __uint_as_float(((unsigned int)h) << 16);
}
__device__ inline floatx4 mfma16(short8 a, short8 b, floatx4 c) {
  return __builtin_amdgcn_mfma_f32_16x16x32_bf16(a, b, c, 0, 0, 0);
}

// async global->LDS, 16B per lane; dest = wave-uniform base + lane*16
__device__ inline void gload16(const ushort* g, ushort* l) {
  __builtin_amdgcn_global_load_lds(
      (const __attribute__((address_space(1))) void*)g,
      (__attribute__((address_space(3))) void*)l, 16, 0, 0);
}

// stage 16 fp32 -> hi/lo bf16 pairs into LDS (base0 role only)
__device__ inline void stage_split16(const float* __restrict__ src, ushort* dsth, ushort* dstl) {
  float fv[16];
  #pragma unroll
  for (int i = 0; i < 4; ++i) *(float4*)&fv[4 * i] = *(const float4*)(src + 4 * i);
  unsigned int ph[8], pl[8];
  #pragma unroll
  for (int i = 0; i < 8; ++i) {
    ushort h0 = f2bf(fv[2 * i]);
    ushort l0 = f2bf(fv[2 * i] - bf2f(h0));
    ushort h1 = f2bf(fv[2 * i + 1]);
    ushort l1 = f2bf(fv[2 * i + 1] - bf2f(h1));
    ph[i] = (unsigned int)h0 | ((unsigned int)h1 << 16);
    pl[i] = (unsigned int)l0 | ((unsigned int)l1 << 16);
  }
  *(uint4*)dsth       = make_uint4(ph[0], ph[1], ph[2], ph[3]);
  *(uint4*)(dsth + 8) = make_uint4(ph[4], ph[5], ph[6], ph[7]);
  *(uint4*)dstl       = make_uint4(pl[0], pl[1], pl[2], pl[3]);
  *(uint4*)(dstl + 8) = make_uint4(pl[4], pl[5], pl[6], pl[7]);
}

// block-reduce then STORE into this block's private bucket (written exactly once).
__device__ inline void cost_store_bucket(float csum, int cnt, float2* __restrict__ cbuf,
                                         int bucket_base) {
  #pragma unroll
  for (int off = 32; off > 0; off >>= 1) {
    csum += __shfl_down(csum, off);
    cnt  += __shfl_down(cnt, off);
  }
  __shared__ float sc[4];
  __shared__ int   si[4];
  int wid = threadIdx.x >> 6;
  if ((threadIdx.x & 63) == 0) { sc[wid] = csum; si[wid] = cnt; }
  __syncthreads();
  if (threadIdx.x == 0) {
    float c = sc[0] + sc[1] + sc[2] + sc[3];
    int   k = si[0] + si[1] + si[2] + si[3];
    float2 v;
    v.x = c * 0.01f;             // per-spike cost = 0.1 * fac/10 * wn = 0.01*fac*wn
    v.y = (float)k;
    cbuf[bucket_base + blockIdx.x] = v;
  }
}

// ---------------- merged setup: base0(K-split) | wnorm | convert ----------------
// bid [0,512):      base0 partial GEMM (m-tile 4 x n-tile 32 x kslice 4)
// bid [512,1408):   wnorm (4 rows/block)
// bid [1408,2688):  convert W1/W2 -> bf16

__global__ __launch_bounds__(256) void setup_kernel(const float* __restrict__ w0,
                                                    const float* __restrict__ w1,
                                                    const float* __restrict__ w2,
                                                    const float* __restrict__ inputs,
                                                    float* __restrict__ wn,
                                                    ushort* __restrict__ w1b,
                                                    ushort* __restrict__ w2b,
                                                    float* __restrict__ P0) {  // [4][256][2048]
  __shared__ ushort Ah[64][72], Al[64][72], Bh[64][72], Bl[64][72];  // base0 role only
  const int bid = blockIdx.x;
  const int tid = threadIdx.x;

  if (bid >= 1408) {
    // ---- convert W1,W2 -> bf16 ----
    int i = ((bid - 1408) * 256 + tid) * 8;   // 1280 blocks -> 2621440 elems
    const float* src; ushort* dst;
    if (i < 2097152) { src = w1 + i; dst = w1b + i; }
    else             { src = w2 + (i - 2097152); dst = w2b + (i - 2097152); }
    float4 a = *(const float4*)src;
    float4 b = *(const float4*)(src + 4);
    unsigned int p0 = (unsigned int)f2bf(a.x) | ((unsigned int)f2bf(a.y) << 16);
    unsigned int p1 = (unsigned int)f2bf(a.z) | ((unsigned int)f2bf(a.w) << 16);
    unsigned int p2 = (unsigned int)f2bf(b.x) | ((unsigned int)f2bf(b.y) << 16);
    unsigned int p3 = (unsigned int)f2bf(b.z) | ((unsigned int)f2bf(b.w) << 16);
    *(uint4*)dst = make_uint4(p0, p1, p2, p3);
    return;
  }
  if (bid >= 512) {
    // ---- wnorm: row r = (bid-512)*4 + wave, per-wave reduction ----
    int r = (bid - 512) * 4 + (tid >> 6);
    int lane = tid & 63;
    const float* row; int K;
    if (r < 2048)      { row = w0 + (size_t)r * 1024;          K = 1024; }
    else if (r < 3072) { row = w1 + (size_t)(r - 2048) * 2048; K = 2048; }
    else               { row = w2 + (size_t)(r - 3072) * 1024; K = 1024; }
    float ss = 0.f;
    for (int k = lane; k < K; k += 64) { float x = row[k]; ss += x * x; }
    #pragma unroll
    for (int off = 32; off > 0; off >>= 1) ss += __shfl_down(ss, off);
    if (lane == 0) wn[r] = sqrtf(ss);
    return;
  }

  // ---- base0 partial: P0[sl] = inputs[:, ks] @ w0[:, ks]^T (split MFMA) ----
  const int m0 = (bid & 3) * 64;
  const int n0 = ((bid >> 2) & 31) * 64;
  const int sl = bid >> 7;                 // 0..3
  const int kbase = sl * 256;
  const int lane = tid & 63, wv = tid >> 6;
  const int wm = wv & 1, wn2 = wv >> 1;
  const int l15 = lane & 15, quad = lane >> 4;
  const int sr = tid >> 2, scol = (tid & 3) * 16;

  floatx4 acc[2][2];
  #pragma unroll
  for (int i = 0; i < 2; ++i)
    #pragma unroll
    for (int j = 0; j < 2; ++j) acc[i][j] = (floatx4){0.f, 0.f, 0.f, 0.f};

  for (int k0 = 0; k0 < 256; k0 += 64) {
    stage_split16(inputs + (size_t)(m0 + sr) * 1024 + kbase + k0 + scol, &Ah[sr][scol], &Al[sr][scol]);
    stage_split16(w0 + (size_t)(n0 + sr) * 1024 + kbase + k0 + scol, &Bh[sr][scol], &Bl[sr][scol]);
    __syncthreads();
    #pragma unroll
    for (int ks = 0; ks < 2; ++ks) {
      short8 ah[2], al[2], bh[2], bl[2];
      #pragma unroll
      for (int s = 0; s < 2; ++s) {
        ah[s] = *(const short8*)&Ah[32 * wm + 16 * s + l15][ks * 32 + quad * 8];
        al[s] = *(const short8*)&Al[32 * wm + 16 * s + l15][ks * 32 + quad * 8];
        bh[s] = *(const short8*)&Bh[32 * wn2 + 16 * s + l15][ks * 32 + quad * 8];
        bl[s] = *(const short8*)&Bl[32 * wn2 + 16 * s + l15][ks * 32 + quad * 8];
      }
      #pragma unroll
      for (int sm = 0; sm < 2; ++sm)
        #pragma unroll
        for (int sn = 0; sn < 2; ++sn) {
          acc[sm][sn] = mfma16(ah[sm], bh[sn], acc[sm][sn]);
          acc[sm][sn] = mfma16(ah[sm], bl[sn], acc[sm][sn]);
          acc[sm][sn] = mfma16(al[sm], bh[sn], acc[sm][sn]);
        }
    }
    __syncthreads();
  }
  float* Ps = P0 + (size_t)sl * 524288;
  #pragma unroll
  for (int sm = 0; sm < 2; ++sm)
    #pragma unroll
    for (int sn = 0; sn < 2; ++sn)
      #pragma unroll
      for (int r = 0; r < 4; ++r) {
        int m = m0 + 32 * wm + 16 * sm + quad * 4 + r;
        int n = n0 + 32 * wn2 + 16 * sn + l15;
        Ps[(size_t)m * 2048 + n] = acc[sm][sn][r];
      }
}

// ---- fused GEMM + LIF: A[4096][K] (rows m=b*16+t) @ W[N][K]^T, LIF in epilogue ----
// Tile BM x 64, BK=64, 4 waves, full K, dbuf LDS, counted-vmcnt depth-2 pipeline.

template<int K, int N, int BM, bool LAST>
__global__ __launch_bounds__(256) void gemm_lif_kernel(const ushort* __restrict__ A,
                                                       const ushort* __restrict__ W,
                                                       const float* __restrict__ cn,
                                                       const float* __restrict__ tn,
                                                       const float* __restrict__ th,
                                                       const float* __restrict__ wnv,
                                                       ushort* __restrict__ spout,  // [4096][N] (b*16+t rows), null if LAST
                                                       float* __restrict__ outF,    // [256][N] if LAST
                                                       float2* __restrict__ cbuf,
                                                       int bucket_base) {
  __shared__ __attribute__((aligned(16))) ushort As[2][BM * 64];
  __shared__ __attribute__((aligned(16))) ushort Bs[2][64 * 64];
  constexpr int NSTEP = K / 64;
  constexpr int NT = N / 64;           // n-tiles
  constexpr int MT = 4096 / BM;        // m-tiles
  constexpr int NWG = MT * NT;         // 512 both GEMMs, divisible by 8
  constexpr int SM = BM / 32;          // acc rows per wave (4 for BM=128, 2 for BM=64)

  // XCD-bijective swizzle
  const int orig = ((int)blockIdx.x % 8) * (NWG / 8) + (int)blockIdx.x / 8;
  const int m0 = (orig / NT) * BM;
  const int n0 = (orig % NT) * 64;

  const int tid = threadIdx.x;
  const int lane = tid & 63, wv = tid >> 6;
  const int wm = wv & 1, wn2 = wv >> 1;
  const int l15 = lane & 15, quad = lane >> 4;

  const ushort* Ab = A + (size_t)m0 * K;
  const ushort* Wb = W + (size_t)n0 * K;

  const int lrow = lane >> 3;                       // 0..7
  const int lslot = (lane & 7) ^ lrow;              // inverse-swizzled source slot

  floatx4 acc[SM][2];
  #pragma unroll
  for (int i = 0; i < SM; ++i)
    #pragma unroll
    for (int j = 0; j < 2; ++j) acc[i][j] = (floatx4){0.f, 0.f, 0.f, 0.f};

  // per wave per stage: SM (A) + 2 (B) gload16 -> LW = SM+2 outstanding per stage
  auto stage = [&](int buf, int k0) {
    #pragma unroll
    for (int h = 0; h < SM; ++h) {                   // A: BM rows = 4 waves x SM x 8
      int r0 = wv * (BM / 4) + h * 8;
      gload16(Ab + (size_t)(r0 + lrow) * K + k0 + lslot * 8, &As[buf][r0 * 64]);
    }
    #pragma unroll
    for (int h = 0; h < 2; ++h) {                    // B: 64 rows = 4 waves x 2 x 8
      int r0 = wv * 16 + h * 8;
      gload16(Wb + (size_t)(r0 + lrow) * K + k0 + lslot * 8, &Bs[buf][r0 * 64]);
    }
  };
  auto compute = [&](int buf) {
    #pragma unroll
    for (int ks = 0; ks < 2; ++ks) {
      short8 af[SM], bf[2];
      #pragma unroll
      for (int s = 0; s < SM; ++s) {
        int arow = wm * (BM / 2) + s * 16 + l15;
        af[s] = *(const short8*)&As[buf][arow * 64 + (((ks * 4 + quad) ^ (arow & 7)) << 3)];
      }
      #pragma unroll
      for (int s = 0; s < 2; ++s) {
        int brow = wn2 * 32 + s * 16 + l15;
        bf[s] = *(const short8*)&Bs[buf][brow * 64 + (((ks * 4 + quad) ^ (brow & 7)) << 3)];
      }
      #pragma unroll
      for (int sm = 0; sm < SM; ++sm)
        #pragma unroll
        for (int sn = 0; sn < 2; ++sn)
          acc[sm][sn] = mfma16(af[sm], bf[sn], acc[sm][sn]);
    }
  };

  // depth-2 prologue: two stages in flight (LW each)
  stage(0, 0);
  stage(1, 64);
  for (int kk = 0; kk < NSTEP; ++kk) {
    int buf = kk & 1;
    // wait for the OLDEST stage (this buf); keep the next stage in flight.
    if (kk + 1 < NSTEP) {
      if constexpr (SM == 4) WAITCNT_VM(6); else WAITCNT_VM(4);
    } else {
      WAITCNT_VM(0);
    }
    SBARRIER();              // all waves: buf ready (each waited its own loads)
    compute(buf);
    if (kk + 2 < NSTEP) {
      SBARRIER();            // all waves done computing buf -> safe to overwrite
      stage(buf, (kk + 2) * 64);
    }
  }

  // ---- epilogue: in-register LIF over t, serialized across quads ----
  float csum = 0.f; int cnt = 0;
  #pragma unroll
  for (int sm = 0; sm < SM; ++sm) {
    const int b = (m0 >> 4) + wm * SM + sm;
    #pragma unroll
    for (int sn = 0; sn < 2; ++sn) {
      const int n = n0 + wn2 * 32 + sn * 16 + l15;
      float cnv[4], tnv[4];
      #pragma unroll
      for (int r = 0; r < 4; ++r) {
        size_t off = (size_t)(quad * 4 + r) * (256 * N) + (size_t)b * N + n;
        cnv[r] = cn[off];
        tnv[r] = tn[off];
      }
      const float thn = th[n];
      const float wnn = wnv[n];
      float V = 0.f; int prev = 0;
      ushort skeep[4] = {0, 0, 0, 0};
      #pragma unroll
      for (int qq = 0; qq < 4; ++qq) {
        float Vl = V; int pl = prev;
        ushort slocal[4];
        #pragma unroll
        for (int r = 0; r < 4; ++r) {
          float cur = acc[sm][sn][r] + cnv[r] * (0.05f * wnn);
          float Vn = pl ? Vl : (0.95f * Vl + cur);
          float thr = thn + tnv[r] * 0.1f;
          bool sp = (!pl) && (Vn > thr);
          Vl = sp ? 0.f : Vn;
          slocal[r] = sp ? (ushort)0x3F80 : (ushort)0;
          pl = sp ? 1 : 0;
        }
        if (quad == qq) {
          #pragma unroll
          for (int r = 0; r < 4; ++r) skeep[r] = slocal[r];
        }
        V = __shfl(Vl, l15 + (qq << 4));
        prev = __shfl(pl, l15 + (qq << 4));
      }
      #pragma unroll
      for (int r = 0; r < 4; ++r) {
        int t = quad * 4 + r + 1;
        float f = (t <= 7) ? 10.f : (float)(17 - t);
        if (skeep[r]) { csum += wnn * f; cnt++; }
      }
      if (!LAST) {
        const int mbase = m0 + wm * (BM / 2) + sm * 16 + quad * 4;
        #pragma unroll
        for (int r = 0; r < 4; ++r)
          spout[(size_t)(mbase + r) * N + n] = skeep[r];
      } else {
        if (quad == 3) outF[(size_t)b * N + n] = skeep[3] ? 1.f : 0.f;  // t=16
      }
    }
  }
  cost_store_bucket(csum, cnt, cbuf, bucket_base);
}

// ---------------- L0 LIF: all 16 steps, state in registers ----------------
// 512 blocks x 256 threads x 4 elems; sums 4 base0 partial slices;
// sp0 written in m = b*16 + (t-1) row layout.

__global__ __launch_bounds__(256) void l0_lif_kernel(const float* __restrict__ P0,  // [4][256][2048]
                                                     const float* __restrict__ cn0,
                                                     const float* __restrict__ tn0,
                                                     const float* __restrict__ th0,
                                                     const float* __restrict__ wn0,
                                                     ushort* __restrict__ sp0,
                                                     float2* __restrict__ cbuf) {
  const int e = (blockIdx.x * 256 + threadIdx.x) * 4;
  const int n = e & 2047;
  const int b = e >> 11;
  float4 b0 = *(const float4*)(P0 + e);
  float4 b1 = *(const float4*)(P0 + 524288 + e);
  float4 b2 = *(const float4*)(P0 + 1048576 + e);
  float4 b3 = *(const float4*)(P0 + 1572864 + e);
  float4 th4 = *(const float4*)(th0 + n);
  float4 wn4 = *(const float4*)(wn0 + n);
  float bbv[4] = {b0.x + b1.x + b2.x + b3.x, b0.y + b1.y + b2.y + b3.y,
                  b0.z + b1.z + b2.z + b3.z, b0.w + b1.w + b2.w + b3.w};
  float thv[4] = {th4.x, th4.y, th4.z, th4.w};
  float wnq[4] = {wn4.x, wn4.y, wn4.z, wn4.w};
  float V[4] = {0.f, 0.f, 0.f, 0.f};
  bool prev[4] = {false, false, false, false};
  float csum = 0.f; int cnt = 0;
  #pragma unroll 2
  for (int t = 1; t <= T_STEPS; ++t) {
    size_t off = (size_t)(t - 1) * 524288 + e;
    float4 c4 = *(const float4*)(cn0 + off);
    float4 t4 = *(const float4*)(tn0 + off);
    float cnv[4] = {c4.x, c4.y, c4.z, c4.w};
    float tnv[4] = {t4.x, t4.y, t4.z, t4.w};
    float f = (t <= 7) ? 10.f : (float)(17 - t);
    ushort sout[4];
    #pragma unroll
    for (int j = 0; j < 4; ++j) {
      float cur = bbv[j] + cnv[j] * (0.05f * wnq[j]);
      float Vn = prev[j] ? V[j] : (0.95f * V[j] + cur);
      float thr = thv[j] + tnv[j] * 0.1f;
      bool sp = (!prev[j]) && (Vn > thr);
      V[j] = sp ? 0.f : Vn;
      sout[j] = sp ? (ushort)0x3F80 : (ushort)0;
      prev[j] = sp;
      if (sp) { csum += wnq[j] * f; cnt++; }
    }
    ushort4 sq; sq.x = sout[0]; sq.y = sout[1]; sq.z = sout[2]; sq.w = sout[3];
    *(ushort4*)(sp0 + (size_t)(b * 16 + t - 1) * 2048 + n) = sq;
  }
  cost_store_bucket(csum, cnt, cbuf, 0);
}

// ---------------- finalize: reduce 1536 buckets -> cost, entropy ----------------

__global__ __launch_bounds__(256) void finalize_kernel(const float2* __restrict__ cbuf,
                                                       float* __restrict__ out) {
  float c = 0.f, k = 0.f;
  for (int i = threadIdx.x; i < 1536; i += 256) {
    float2 v = cbuf[i];
    c += v.x; k += v.y;
  }
  #pragma unroll
  for (int off = 32; off > 0; off >>= 1) {
    c += __shfl_down(c, off);
    k += __shfl_down(k, off);
  }
  __shared__ float sc[4], sk[4];
  int wid = threadIdx.x >> 6;
  if ((threadIdx.x & 63) == 0) { sc[wid] = c; sk[wid] = k; }
  __syncthreads();
  if (threadIdx.x == 0) {
    float cost = sc[0] + sc[1] + sc[2] + sc[3];
    float tot  = sk[0] + sk[1] + sk[2] + sk[3];
    float p1 = tot / 14680064.f;   // T*B*(2048+1024+512)
    float p0 = 1.f - p1;
    float ent = -(p1 * log2f(p1 + 1e-12f) + p0 * log2f(p0 + 1e-12f));
    out[131072] = cost;
    out[131073] = ent;
  }
}

// ---------------- launch ----------------

extern "C" void kernel_launch(void* const* d_in, const int* in_sizes, int n_in,
                              void* d_out, int out_size, void* d_ws, size_t ws_size,
                              hipStream_t stream) {
  const float* inputs = (const float*)d_in[0];
  const float* w0  = (const float*)d_in[1];
  const float* th0 = (const float*)d_in[2];
  const float* cn0 = (const float*)d_in[3];
  const float* tn0 = (const float*)d_in[4];
  const float* w1  = (const float*)d_in[5];
  const float* th1 = (const float*)d_in[6];
  const float* cn1 = (const float*)d_in[7];
  const float* tn1 = (const float*)d_in[8];
  const float* w2  = (const float*)d_in[9];
  const float* th2 = (const float*)d_in[10];
  const float* cn2 = (const float*)d_in[11];
  const float* tn2 = (const float*)d_in[12];
  float* out = (float*)d_out;
  float* ws  = (float*)d_ws;

  // workspace layout (float slots), ~41 MB total
  float* wn    = ws;                        // 4096 (3584 used)
  float* P0    = ws + 4096;                 // 2097152 fp32 [4][256][2048] (8 MB)
  ushort* w1b  = (ushort*)(P0 + 2097152);   // 2097152 ushort [1024][2048]
  ushort* w2b  = w1b + 2097152;             // 524288 ushort [512][1024]
  ushort* sp0  = w2b + 524288;              // 8388608 ushort [4096][2048] (m=b*16+t)
  ushort* sp1  = sp0 + 8388608;             // 4194304 ushort [4096][1024] (m=b*16+t)
  float2* cbuf = (float2*)(sp1 + 4194304);  // 1536 float2

  // setup: base0 K-split (512) | wnorm (896) | convert (1280) = 2688 blocks
  setup_kernel<<<2688, 256, 0, stream>>>(w0, w1, w2, inputs, wn, w1b, w2b, P0);

  // L0: all 16 steps (sums 4 P0 slices) -> sp0 (b*16+t layout), buckets [0,512)
  l0_lif_kernel<<<512, 256, 0, stream>>>(P0, cn0, tn0, th0, wn, sp0, cbuf);

  // GEMM1 + LIF1 (tile 128x64, 512 blocks): sp1 = LIF(sp0 @ w1b^T), buckets [512,1024)
  gemm_lif_kernel<2048, 1024, 128, false><<<512, 256, 0, stream>>>(
      sp0, w1b, cn1, tn1, th1, wn + 2048, sp1, nullptr, cbuf, 512);

  // GEMM2 + LIF2 (tile 64x64, 512 blocks): out = LIF(sp1 @ w2b^T) at t=16,
  // buckets [1024,1536)
  gemm_lif_kernel<1024, 512, 64, true><<<512, 256, 0, stream>>>(
      sp1, w2b, cn2, tn2, th2, wn + 3072, nullptr, out, cbuf, 1024);

  finalize_kernel<<<1, 256, 0, stream>>>(cbuf, out);
}